// Round 4
// baseline (406.436 us; speedup 1.0000x reference)
//
#include <hip/hip_runtime.h>
#include <hip/hip_bf16.h>

// M=2 branches, K=3 diffusion, N=64, I=1, H=64, B=8, T=12

typedef __attribute__((ext_vector_type(8))) short short8;   // 8 bf16 (4 VGPRs)
typedef __attribute__((ext_vector_type(4))) float f32x4;    // 4 fp32

__device__ __forceinline__ short bf16_hi_trunc(float f) {
    union { float f; unsigned u; } v; v.f = f;
    return (short)(v.u >> 16);
}
__device__ __forceinline__ float trunc_bf16_f32(float f) {
    union { float f; unsigned u; } v; v.f = f;
    v.u &= 0xFFFF0000u;
    return v.f;
}
__device__ __forceinline__ short bf16_rne(float f) {
    union { float f; unsigned u; } v; v.f = f;
    unsigned r = ((v.u >> 16) & 1u) + 0x7FFFu;
    return (short)((v.u + r) >> 16);
}
__device__ __forceinline__ float from_bf16(unsigned short s) {
    union { unsigned u; float f; } v; v.u = ((unsigned)s) << 16;
    return v.f;
}
// sigmoid = 1/(1+2^(-x*log2e)) : mul, exp2, add, rcp
__device__ __forceinline__ float sigmoidf_(float x) {
    float e = __builtin_amdgcn_exp2f(x * -1.442695041f);
    return __builtin_amdgcn_rcpf(1.f + e);
}
// tanh = 1 - 2/(2^(2x*log2e)+1) : mul, exp2, add, rcp, fma
__device__ __forceinline__ float tanhf_(float x) {
    float e2 = __builtin_amdgcn_exp2f(x * 2.885390082f);
    return fmaf(-2.f, __builtin_amdgcn_rcpf(e2 + 1.f), 1.f);
}

// ---------------- prep: pack W, G^T, Whh into MFMA fragment order ----------
// Wf [layer][br][d][ht][kk][lane][8] : 147456/plane
// Gf [br][et][kk][lane][8]           : 24576/plane
// Whf[br][kt][gg][w][lane][8]        : 32768/plane  (B[k][gate] of WhhT)
__global__ __launch_bounds__(256) void k_prep(
    const float* __restrict__ G, const float* __restrict__ W0,
    const float* __restrict__ W1, const float* __restrict__ whh,
    short* __restrict__ Wfhi, short* __restrict__ Wflo,
    short* __restrict__ Gfhi, short* __restrict__ Gflo,
    short* __restrict__ Whfhi, short* __restrict__ Whflo)
{
    int idx = blockIdx.x * 256 + threadIdx.x;
    float v; short *dh, *dl; int didx;
    if (idx < 147456) {
        int j = idx & 7, lane = (idx >> 3) & 63, kk = (idx >> 9) % 6;
        int t2 = idx / 3072;
        int ht = t2 & 3; t2 >>= 2;
        int d = t2 % 3; t2 /= 3;
        int br = t2 & 1, layer = t2 >> 1;
        int k = kk * 32 + ((lane >> 4) << 3) + j;
        int o = k >> 6, l = k & 63, h = ht * 16 + (lane & 15);
        const float* Wp = layer ? W1 : W0;
        v = Wp[((size_t)br * 576 + (o * 3 + d) * 64 + l) * 64 + h];
        dh = Wfhi; dl = Wflo; didx = idx;
    } else if (idx < 172032) {
        int i2 = idx - 147456;
        int j = i2 & 7, lane = (i2 >> 3) & 63, kk = (i2 >> 9) % 6;
        int t2 = i2 / 3072;
        int et = t2 & 3, br = t2 >> 2;
        int k = kk * 32 + ((lane >> 4) << 3) + j;
        int d = k >> 6, c = k & 63, e = et * 16 + (lane & 15);
        v = G[(((size_t)br * 3 + d) * 64 + c) * 64 + e];
        dh = Gfhi; dl = Gflo; didx = i2;
    } else {
        int i3 = idx - 172032;
        int j = i3 & 7, lane = (i3 >> 3) & 63;
        int w = (i3 >> 9) & 3, gg = (i3 >> 11) & 3;
        int kt = (i3 >> 13) & 1, br = (i3 >> 14) & 1;
        int gate = gg * 64 + w * 16 + (lane & 15);
        int k = kt * 32 + ((lane >> 4) << 3) + j;
        v = whh[((size_t)br * 256 + gate) * 64 + k];
        dh = Whfhi; dl = Whflo; didx = i3;
    }
    dh[didx] = bf16_hi_trunc(v);
    dl[didx] = bf16_rne(v - trunc_bf16_f32(v));
}

// ---------------- LSTM: 8 waves/block, streamed Whh frags ------------------
// Block = (br, b, o): 64 sequences. Wave ww = (sh = seq-half, w = hid-slice).
// Thread owns seqs {sh*32 + mt*16 + q*4 + r : mt<2, r<4}, hid = w*16 + r16,
// with all 4 gate types per hid in acc[mt][gg].
__global__ __launch_bounds__(512, 4) void k_lstm(
    const float* __restrict__ x, const short* __restrict__ Whfhi,
    const short* __restrict__ Whflo, const float* __restrict__ wih,
    const float* __restrict__ bih, const float* __restrict__ bhh,
    short* __restrict__ Xhi, short* __restrict__ Xlo)
{
    __shared__ short hbuf[2][2][64][64];  // [dbuf][hi/lo][seq][hid ^ swz]
    const int tid = threadIdx.x;
    const int lane = tid & 63;
    const int ww = __builtin_amdgcn_readfirstlane(tid >> 6);
    const int sh = ww >> 2;           // seq half 0..1
    const int w = ww & 3;             // hid slice 0..3
    const int q = lane >> 4;
    const int r16 = lane & 15;
    const int br = blockIdx.y;
    const int b = blockIdx.x >> 6, o = blockIdx.x & 63;

    float wihv[4], biasv[4];
#pragma unroll
    for (int gg = 0; gg < 4; ++gg) {
        const int gate = gg * 64 + w * 16 + r16;
        wihv[gg] = wih[br * 256 + gate];
        biasv[gg] = bih[br * 256 + gate] + bhh[br * 256 + gate];
    }

    float cst[2][4];
#pragma unroll
    for (int mt = 0; mt < 2; ++mt)
#pragma unroll
        for (int r = 0; r < 4; ++r) cst[mt][r] = 0.f;

    const float* xb = x + (((size_t)b * 12) * 64 + o) * 64 + sh * 32;
    const size_t hob = ((size_t)(br * 8 + b) * 64 + o) * 4096;
    const short* wfh0 = Whfhi + (size_t)br * 16384;
    const short* wfl0 = Whflo + (size_t)br * 16384;

    for (int t = 0; t < 12; ++t) {
        f32x4 acc[2][4];   // [mt][gg]
        const float* xrow = xb + (size_t)t * 4096;
        float4 xv0 = *(const float4*)(xrow + q * 4);
        float4 xv1 = *(const float4*)(xrow + 16 + q * 4);
        float xm[2][4] = {{xv0.x, xv0.y, xv0.z, xv0.w},
                          {xv1.x, xv1.y, xv1.z, xv1.w}};
#pragma unroll
        for (int mt = 0; mt < 2; ++mt)
#pragma unroll
            for (int r = 0; r < 4; ++r)
#pragma unroll
                for (int gg = 0; gg < 4; ++gg)
                    acc[mt][gg][r] = fmaf(xm[mt][r], wihv[gg], biasv[gg]);

        if (t > 0) {
            const short* hb = &hbuf[t & 1][0][0][0];
            const short* wfh = wfh0;
            const short* wfl = wfl0;
            // keep the weight-frag loads inside the loop (no cross-step CSE)
            asm volatile("" : "+v"(wfh), "+v"(wfl));
#pragma unroll
            for (int kt = 0; kt < 2; ++kt) {
                short8 Bh[4], Bl[4];
#pragma unroll
                for (int gg = 0; gg < 4; ++gg) {
                    const int bidx = (((kt * 4 + gg) * 4 + w) * 64 + lane) * 8;
                    Bh[gg] = *(const short8*)(wfh + bidx);
                    Bl[gg] = *(const short8*)(wfl + bidx);
                }
                short8 Ah[2], Al[2];
#pragma unroll
                for (int mt = 0; mt < 2; ++mt) {
                    const int row = sh * 32 + mt * 16 + r16;
                    const int elem = row * 64 +
                                     ((kt * 32 + q * 8) ^ ((r16 & 7) << 3));
                    Ah[mt] = *(const short8*)(hb + elem);
                    Al[mt] = *(const short8*)(hb + 4096 + elem);
                }
#pragma unroll
                for (int mt = 0; mt < 2; ++mt)
#pragma unroll
                    for (int gg = 0; gg < 4; ++gg) {
                        acc[mt][gg] = __builtin_amdgcn_mfma_f32_16x16x32_bf16(
                            Ah[mt], Bh[gg], acc[mt][gg], 0, 0, 0);
                        acc[mt][gg] = __builtin_amdgcn_mfma_f32_16x16x32_bf16(
                            Ah[mt], Bl[gg], acc[mt][gg], 0, 0, 0);
                        acc[mt][gg] = __builtin_amdgcn_mfma_f32_16x16x32_bf16(
                            Al[mt], Bh[gg], acc[mt][gg], 0, 0, 0);
                    }
            }
        }
        short* hw = &hbuf[(t + 1) & 1][0][0][0];
        const int hid = w * 16 + r16;
#pragma unroll
        for (int mt = 0; mt < 2; ++mt) {
#pragma unroll
            for (int r = 0; r < 4; ++r) {
                float ig = sigmoidf_(acc[mt][0][r]);
                float fg = sigmoidf_(acc[mt][1][r]);
                float gt = tanhf_(acc[mt][2][r]);
                float og = sigmoidf_(acc[mt][3][r]);
                float c = fmaf(fg, cst[mt][r], ig * gt);
                cst[mt][r] = c;
                float hv = og * tanhf_(c);
                int seq = sh * 32 + mt * 16 + q * 4 + r;
                if (t == 11) {
                    Xhi[hob + seq * 64 + hid] = bf16_hi_trunc(hv);
                    Xlo[hob + seq * 64 + hid] = bf16_rne(hv - trunc_bf16_f32(hv));
                } else {
                    int elem = seq * 64 + (hid ^ ((seq & 7) << 3));
                    hw[elem] = bf16_hi_trunc(hv);
                    hw[4096 + elem] = bf16_rne(hv - trunc_bf16_f32(hv));
                }
            }
        }
        __syncthreads();
    }
}

// ---------------- T1 (VALU fp32, hi/lo bf16 I/O) ---------------------------
// T1[br][o][b][m][cl] = sum_n G[br][o][n][m] * X[br][b][n][cl]
__global__ __launch_bounds__(256) void k_t1(
    const short* __restrict__ Xhi, const short* __restrict__ Xlo,
    const float* __restrict__ G,
    short* __restrict__ T1hi, short* __restrict__ T1lo)
{
    const int br = blockIdx.z;
    const int o = blockIdx.y >> 3, b = blockIdx.y & 7;
    const int cl = blockIdx.x * 256 + threadIdx.x;
    const unsigned short* xh = (const unsigned short*)Xhi;
    const unsigned short* xl = (const unsigned short*)Xlo;
    const size_t xb = ((size_t)(br * 8 + b) * 64) * 4096 + cl;
    const float* gp = G + ((size_t)(br * 3 + o) * 64) * 64;
    float acc[64];
#pragma unroll
    for (int mm = 0; mm < 64; ++mm) acc[mm] = 0.f;
#pragma unroll 4
    for (int n = 0; n < 64; ++n) {
        float xv = from_bf16(xh[xb + (size_t)n * 4096]) +
                   from_bf16(xl[xb + (size_t)n * 4096]);
        const float* gr = gp + n * 64;
#pragma unroll
        for (int mm = 0; mm < 64; ++mm) acc[mm] = fmaf(xv, gr[mm], acc[mm]);
    }
    const size_t tb = (((size_t)(br * 3 + o) * 8 + b) * 64) * 4096 + cl;
#pragma unroll
    for (int mm = 0; mm < 64; ++mm) {
        float f = acc[mm];
        T1hi[tb + (size_t)mm * 4096] = bf16_hi_trunc(f);
        T1lo[tb + (size_t)mm * 4096] = bf16_rne(f - trunc_bf16_f32(f));
    }
}

// ---------------- T2 + FC (MFMA) -------------------------------------------
__global__ __launch_bounds__(256) void k_t2fc(
    const short* __restrict__ T1hi, const short* __restrict__ T1lo,
    const short* __restrict__ Wfhi, const short* __restrict__ Wflo,
    const short* __restrict__ Gfhi, const short* __restrict__ Gflo,
    const float* __restrict__ bias, const float* __restrict__ fcW,
    const float* __restrict__ fcb,
    short* __restrict__ Yhi, short* __restrict__ Ylo,
    float* __restrict__ yws, int last)
{
    __shared__ short ldsU[2][3][64][72];   // [plane][d][h][c] (+pad)
    short* u0 = &ldsU[0][0][0][0];
    short* u1 = &ldsU[1][0][0][0];
    const int tid = threadIdx.x, lane = tid & 63;
    const int r16 = lane & 15, q = lane >> 4;
    const int w = __builtin_amdgcn_readfirstlane(tid >> 6);
    const int m = blockIdx.x, b = blockIdx.y, br = blockIdx.z;

    // ---- phase 1: U = T1 @ W (wave w owns c-tile w)
    f32x4 acc1[3][4];
#pragma unroll
    for (int d = 0; d < 3; ++d)
#pragma unroll
        for (int ht = 0; ht < 4; ++ht)
#pragma unroll
            for (int r = 0; r < 4; ++r) acc1[d][ht][r] = 0.f;

    const size_t t1b = (((size_t)br * 3 * 8 + b) * 64 + m) * 4096;
#pragma unroll
    for (int kk = 0; kk < 6; ++kk) {
        const int o = kk >> 1;
        const size_t aoff = t1b + (size_t)o * (8 * 64 * 4096) +
                            (w * 16 + r16) * 64 + (kk & 1) * 32 + q * 8;
        short8 Ah = *(const short8*)(T1hi + aoff);
        short8 Al = *(const short8*)(T1lo + aoff);
#pragma unroll
        for (int d = 0; d < 3; ++d) {
#pragma unroll
            for (int ht = 0; ht < 4; ++ht) {
                const int widx = ((((br * 3 + d) * 4 + ht) * 6 + kk) << 9) + lane * 8;
                short8 Bh = *(const short8*)(Wfhi + widx);
                short8 Bl = *(const short8*)(Wflo + widx);
                acc1[d][ht] = __builtin_amdgcn_mfma_f32_16x16x32_bf16(
                    Ah, Bh, acc1[d][ht], 0, 0, 0);
                acc1[d][ht] = __builtin_amdgcn_mfma_f32_16x16x32_bf16(
                    Ah, Bl, acc1[d][ht], 0, 0, 0);
                acc1[d][ht] = __builtin_amdgcn_mfma_f32_16x16x32_bf16(
                    Al, Bh, acc1[d][ht], 0, 0, 0);
            }
        }
    }
#pragma unroll
    for (int d = 0; d < 3; ++d)
#pragma unroll
        for (int ht = 0; ht < 4; ++ht)
#pragma unroll
            for (int r = 0; r < 4; ++r) {
                float f = acc1[d][ht][r];
                int c = w * 16 + q * 4 + r;
                int h = ht * 16 + r16;
                int ui = (d * 64 + h) * 72 + c;
                u0[ui] = bf16_hi_trunc(f);
                u1[ui] = bf16_rne(f - trunc_bf16_f32(f));
            }
    __syncthreads();

    // ---- phase 2: out = G^T @ U + bias (wave w owns e-tile w)
    f32x4 acc2[4];
#pragma unroll
    for (int ht = 0; ht < 4; ++ht) {
        float bb = bias[br * 64 + ht * 16 + r16];
#pragma unroll
        for (int r = 0; r < 4; ++r) acc2[ht][r] = bb;
    }
#pragma unroll
    for (int kk = 0; kk < 6; ++kk) {
        const int gi = (((br * 4 + w) * 6 + kk) << 9) + lane * 8;
        short8 A2h = *(const short8*)(Gfhi + gi);
        short8 A2l = *(const short8*)(Gflo + gi);
        const int d = kk >> 1, cb = (kk & 1) * 32 + q * 8;
#pragma unroll
        for (int ht = 0; ht < 4; ++ht) {
            const int bi = (d * 64 + ht * 16 + r16) * 72 + cb;
            short8 B2h = *(const short8*)(u0 + bi);
            short8 B2l = *(const short8*)(u1 + bi);
            acc2[ht] = __builtin_amdgcn_mfma_f32_16x16x32_bf16(
                A2h, B2h, acc2[ht], 0, 0, 0);
            acc2[ht] = __builtin_amdgcn_mfma_f32_16x16x32_bf16(
                A2h, B2l, acc2[ht], 0, 0, 0);
            acc2[ht] = __builtin_amdgcn_mfma_f32_16x16x32_bf16(
                A2l, B2h, acc2[ht], 0, 0, 0);
        }
    }

    if (!last) {
        __syncthreads();
        float* ldsO = (float*)u0;   // 16 KB, fits in plane 0
#pragma unroll
        for (int ht = 0; ht < 4; ++ht)
#pragma unroll
            for (int r = 0; r < 4; ++r)
                ldsO[(w * 16 + q * 4 + r) * 64 + ht * 16 + r16] = acc2[ht][r];
        __syncthreads();
        const size_t yb = ((size_t)(br * 8 + b) * 64 + m) * 4096;
        const int i0 = tid * 16;
#pragma unroll
        for (int half = 0; half < 2; ++half) {
            short8 h8, l8;
#pragma unroll
            for (int ii = 0; ii < 8; ++ii) {
                float f = ldsO[i0 + half * 8 + ii];
                h8[ii] = bf16_hi_trunc(f);
                l8[ii] = bf16_rne(f - trunc_bf16_f32(f));
            }
            *(short8*)(Yhi + yb + i0 + half * 8) = h8;
            *(short8*)(Ylo + yb + i0 + half * 8) = l8;
        }
    } else {
        float p[4];
#pragma unroll
        for (int r = 0; r < 4; ++r) {
            p[r] = 0.f;
#pragma unroll
            for (int ht = 0; ht < 4; ++ht)
                p[r] += acc2[ht][r] * fcW[br * 64 + ht * 16 + r16];
        }
#pragma unroll
        for (int off = 1; off < 16; off <<= 1)
#pragma unroll
            for (int r = 0; r < 4; ++r) p[r] += __shfl_xor(p[r], off);
        if (r16 == 0) {
            float fb = fcb[br];
#pragma unroll
            for (int r = 0; r < 4; ++r) {
                int e = w * 16 + q * 4 + r;
                yws[(size_t)br * 32768 + (size_t)b * 4096 + m * 64 + e] =
                    fmaxf(p[r] + fb, 0.f);
            }
        }
    }
}

__global__ __launch_bounds__(256) void k_mean(
    const float* __restrict__ yws, float* __restrict__ out)
{
    int idx = blockIdx.x * 256 + threadIdx.x;
    out[idx] = 0.5f * (yws[idx] + yws[32768 + idx]);
}

extern "C" void kernel_launch(void* const* d_in, const int* in_sizes, int n_in,
                              void* d_out, int out_size, void* d_ws, size_t ws_size,
                              hipStream_t stream)
{
    const float* x   = (const float*)d_in[0];
    const float* G   = (const float*)d_in[1];
    const float* wih = (const float*)d_in[2];
    const float* whh = (const float*)d_in[3];
    const float* bih = (const float*)d_in[4];
    const float* bhh = (const float*)d_in[5];
    const float* W0  = (const float*)d_in[6];
    const float* b0  = (const float*)d_in[7];
    const float* W1  = (const float*)d_in[8];
    const float* b1  = (const float*)d_in[9];
    const float* fcW = (const float*)d_in[10];
    const float* fcb = (const float*)d_in[11];
    float* out = (float*)d_out;

    // ws layout (shorts unless noted). Total ~68.2 MB.
    short* Xhi   = (short*)d_ws;            // 4,194,304
    short* Xlo   = Xhi + 4194304;
    short* T1hi  = Xlo + 4194304;           // 12,582,912
    short* T1lo  = T1hi + 12582912;
    float* yws   = (float*)(T1lo + 12582912);  // 65,536 f32
    short* Wfhi  = (short*)(yws + 65536);   // 147,456
    short* Wflo  = Wfhi + 147456;
    short* Gfhi  = Wflo + 147456;           // 24,576
    short* Gflo  = Gfhi + 24576;
    short* Whfhi = Gflo + 24576;            // 32,768
    short* Whflo = Whfhi + 32768;
    short* Y1hi  = Xhi;                     // reuse (X dead after layer-1 k_t1)
    short* Y1lo  = Xlo;

    k_prep<<<800, 256, 0, stream>>>(G, W0, W1, whh,
                                    Wfhi, Wflo, Gfhi, Gflo, Whfhi, Whflo);
    k_lstm<<<dim3(512, 2), 512, 0, stream>>>(x, Whfhi, Whflo, wih, bih, bhh,
                                             Xhi, Xlo);

    // layer 1
    k_t1<<<dim3(16, 24, 2), 256, 0, stream>>>(Xhi, Xlo, G, T1hi, T1lo);
    k_t2fc<<<dim3(64, 8, 2), 256, 0, stream>>>(T1hi, T1lo, Wfhi, Wflo,
                                               Gfhi, Gflo, b0, fcW, fcb,
                                               Y1hi, Y1lo, yws, 0);
    // layer 2
    k_t1<<<dim3(16, 24, 2), 256, 0, stream>>>(Y1hi, Y1lo, G, T1hi, T1lo);
    k_t2fc<<<dim3(64, 8, 2), 256, 0, stream>>>(T1hi, T1lo,
                                               Wfhi + 73728, Wflo + 73728,
                                               Gfhi, Gflo, b1, fcW, fcb,
                                               (short*)nullptr, (short*)nullptr,
                                               yws, 1);
    k_mean<<<128, 256, 0, stream>>>(yws, out);
}

// Round 5
// 328.129 us; speedup vs baseline: 1.2386x; 1.2386x over previous
//
#include <hip/hip_runtime.h>
#include <hip/hip_bf16.h>

// M=2 branches, K=3 diffusion, N=64, I=1, H=64, B=8, T=12

typedef __attribute__((ext_vector_type(8))) short short8;   // 8 bf16 (4 VGPRs)
typedef __attribute__((ext_vector_type(4))) float f32x4;    // 4 fp32

__device__ __forceinline__ short bf16_hi_trunc(float f) {
    union { float f; unsigned u; } v; v.f = f;
    return (short)(v.u >> 16);
}
__device__ __forceinline__ float trunc_bf16_f32(float f) {
    union { float f; unsigned u; } v; v.f = f;
    v.u &= 0xFFFF0000u;
    return v.f;
}
__device__ __forceinline__ short bf16_rne(float f) {
    union { float f; unsigned u; } v; v.f = f;
    unsigned r = ((v.u >> 16) & 1u) + 0x7FFFu;
    return (short)((v.u + r) >> 16);
}
__device__ __forceinline__ float from_bf16(unsigned short s) {
    union { unsigned u; float f; } v; v.u = ((unsigned)s) << 16;
    return v.f;
}
__device__ __forceinline__ float sigmoidf_(float x) {
    float e = __builtin_amdgcn_exp2f(x * -1.442695041f);
    return __builtin_amdgcn_rcpf(1.f + e);
}
__device__ __forceinline__ float tanhf_(float x) {
    float e2 = __builtin_amdgcn_exp2f(x * 2.885390082f);
    return fmaf(-2.f, __builtin_amdgcn_rcpf(e2 + 1.f), 1.f);
}

// ---------------- prep: pack W, G^T, Whh into MFMA fragment order ----------
// Wf [layer][br][d][ht][kk][lane][8] : 147456/plane
// Gf [br][et][kk][lane][8]           : 24576/plane
// Whf[br][kt][gg][w][lane][8]        : 32768/plane  (B[k][gate] of WhhT)
__global__ __launch_bounds__(256) void k_prep(
    const float* __restrict__ G, const float* __restrict__ W0,
    const float* __restrict__ W1, const float* __restrict__ whh,
    short* __restrict__ Wfhi, short* __restrict__ Wflo,
    short* __restrict__ Gfhi, short* __restrict__ Gflo,
    short* __restrict__ Whfhi, short* __restrict__ Whflo)
{
    int idx = blockIdx.x * 256 + threadIdx.x;
    float v; short *dh, *dl; int didx;
    if (idx < 147456) {
        int j = idx & 7, lane = (idx >> 3) & 63, kk = (idx >> 9) % 6;
        int t2 = idx / 3072;
        int ht = t2 & 3; t2 >>= 2;
        int d = t2 % 3; t2 /= 3;
        int br = t2 & 1, layer = t2 >> 1;
        int k = kk * 32 + ((lane >> 4) << 3) + j;
        int o = k >> 6, l = k & 63, h = ht * 16 + (lane & 15);
        const float* Wp = layer ? W1 : W0;
        v = Wp[((size_t)br * 576 + (o * 3 + d) * 64 + l) * 64 + h];
        dh = Wfhi; dl = Wflo; didx = idx;
    } else if (idx < 172032) {
        int i2 = idx - 147456;
        int j = i2 & 7, lane = (i2 >> 3) & 63, kk = (i2 >> 9) % 6;
        int t2 = i2 / 3072;
        int et = t2 & 3, br = t2 >> 2;
        int k = kk * 32 + ((lane >> 4) << 3) + j;
        int d = k >> 6, c = k & 63, e = et * 16 + (lane & 15);
        v = G[(((size_t)br * 3 + d) * 64 + c) * 64 + e];
        dh = Gfhi; dl = Gflo; didx = i2;
    } else {
        int i3 = idx - 172032;
        int j = i3 & 7, lane = (i3 >> 3) & 63;
        int w = (i3 >> 9) & 3, gg = (i3 >> 11) & 3;
        int kt = (i3 >> 13) & 1, br = (i3 >> 14) & 1;
        int gate = gg * 64 + w * 16 + (lane & 15);
        int k = kt * 32 + ((lane >> 4) << 3) + j;
        v = whh[((size_t)br * 256 + gate) * 64 + k];
        dh = Whfhi; dl = Whflo; didx = i3;
    }
    dh[didx] = bf16_hi_trunc(v);
    dl[didx] = bf16_rne(v - trunc_bf16_f32(v));
}

// ---------------- LSTM: 128 seqs/block, 16 waves, LDS-resident weights -----
// Block = (br, b, o-pair): 128 sequences (rows). row = o_local*64 + d.
// Wave ww: sh = ww>>2 (seq quarter, 32 rows), w = ww&3 (hid/gate 16-slice).
// Thread owns rows {sh*32 + mt*16 + q*4 + r}, hid = w*16 + r16.
__global__ __launch_bounds__(1024, 4) void k_lstm(
    const float* __restrict__ x, const short* __restrict__ Whfhi,
    const short* __restrict__ Whflo, const float* __restrict__ wih,
    const float* __restrict__ bih, const float* __restrict__ bhh,
    short* __restrict__ Xhi, short* __restrict__ Xlo)
{
    __shared__ short wlds[2][16384];    // [plane][fragment order]  64 KB
    __shared__ short hbuf[2][128][64];  // [plane][row][hid ^ swz]  32 KB
    const int tid = threadIdx.x;
    const int lane = tid & 63;
    const int ww = __builtin_amdgcn_readfirstlane(tid >> 6);  // 0..15
    const int sh = ww >> 2;
    const int w = ww & 3;
    const int q = lane >> 4;
    const int r16 = lane & 15;
    const int br = blockIdx.y;
    const int b = blockIdx.x >> 5, o2 = blockIdx.x & 31;

    // stage Whh fragment tables into LDS (one-time, coalesced)
    {
        const short* s0 = Whfhi + (size_t)br * 16384 + tid * 16;
        const short* s1 = Whflo + (size_t)br * 16384 + tid * 16;
        *(short8*)&wlds[0][tid * 16] = *(const short8*)s0;
        *(short8*)&wlds[0][tid * 16 + 8] = *(const short8*)(s0 + 8);
        *(short8*)&wlds[1][tid * 16] = *(const short8*)s1;
        *(short8*)&wlds[1][tid * 16 + 8] = *(const short8*)(s1 + 8);
    }

    float wihv[4], biasv[4];
#pragma unroll
    for (int gg = 0; gg < 4; ++gg) {
        const int gate = gg * 64 + w * 16 + r16;
        wihv[gg] = wih[br * 256 + gate];
        biasv[gg] = bih[br * 256 + gate] + bhh[br * 256 + gate];
    }

    float cst[2][4];
#pragma unroll
    for (int mt = 0; mt < 2; ++mt)
#pragma unroll
        for (int r = 0; r < 4; ++r) cst[mt][r] = 0.f;

    // x[(b*12+t)*4096 + o2*128 + row]; rows contiguous per block.
    const float* xb = x + (size_t)b * 12 * 4096 + o2 * 128 + sh * 32;
    // out: ((br*8+b)*262144) + o2*8192 + row*64 + hid
    const size_t hob = (size_t)(br * 8 + b) * 262144 + (size_t)o2 * 8192;
    const int hid = w * 16 + r16;

    __syncthreads();   // weights staged

    for (int t = 0; t < 12; ++t) {
        f32x4 acc[2][4];   // [mt][gg]
        const float* xrow = xb + (size_t)t * 4096;
        float4 xv0 = *(const float4*)(xrow + q * 4);
        float4 xv1 = *(const float4*)(xrow + 16 + q * 4);
        float xm[2][4] = {{xv0.x, xv0.y, xv0.z, xv0.w},
                          {xv1.x, xv1.y, xv1.z, xv1.w}};
#pragma unroll
        for (int mt = 0; mt < 2; ++mt)
#pragma unroll
            for (int r = 0; r < 4; ++r)
#pragma unroll
                for (int gg = 0; gg < 4; ++gg)
                    acc[mt][gg][r] = fmaf(xm[mt][r], wihv[gg], biasv[gg]);

        if (t > 0) {
#pragma unroll 1
            for (int kt = 0; kt < 2; ++kt) {
                short8 Bh[4], Bl[4];
#pragma unroll
                for (int gg = 0; gg < 4; ++gg) {
                    const int bidx = (((kt * 4 + gg) * 4 + w) * 64 + lane) * 8;
                    Bh[gg] = *(const short8*)&wlds[0][bidx];
                    Bl[gg] = *(const short8*)&wlds[1][bidx];
                }
                short8 Ah[2], Al[2];
#pragma unroll
                for (int mt = 0; mt < 2; ++mt) {
                    const int row = sh * 32 + mt * 16 + r16;
                    const int col = (kt * 32 + q * 8) ^ ((r16 & 7) << 3);
                    Ah[mt] = *(const short8*)&hbuf[0][row][col];
                    Al[mt] = *(const short8*)&hbuf[1][row][col];
                }
#pragma unroll
                for (int mt = 0; mt < 2; ++mt)
#pragma unroll
                    for (int gg = 0; gg < 4; ++gg) {
                        acc[mt][gg] = __builtin_amdgcn_mfma_f32_16x16x32_bf16(
                            Ah[mt], Bh[gg], acc[mt][gg], 0, 0, 0);
                        acc[mt][gg] = __builtin_amdgcn_mfma_f32_16x16x32_bf16(
                            Ah[mt], Bl[gg], acc[mt][gg], 0, 0, 0);
                        acc[mt][gg] = __builtin_amdgcn_mfma_f32_16x16x32_bf16(
                            Al[mt], Bh[gg], acc[mt][gg], 0, 0, 0);
                    }
            }
        }
        // activations (torch gate order i,f,g,o)
        float hv_[2][4];
#pragma unroll
        for (int mt = 0; mt < 2; ++mt) {
#pragma unroll
            for (int r = 0; r < 4; ++r) {
                float ig = sigmoidf_(acc[mt][0][r]);
                float fg = sigmoidf_(acc[mt][1][r]);
                float gt = tanhf_(acc[mt][2][r]);
                float og = sigmoidf_(acc[mt][3][r]);
                float c = fmaf(fg, cst[mt][r], ig * gt);
                cst[mt][r] = c;
                hv_[mt][r] = og * tanhf_(c);
            }
        }
        __syncthreads();   // all reads of hbuf done
        if (t == 11) {
#pragma unroll
            for (int mt = 0; mt < 2; ++mt)
#pragma unroll
                for (int r = 0; r < 4; ++r) {
                    int row = sh * 32 + mt * 16 + q * 4 + r;
                    float hv = hv_[mt][r];
                    Xhi[hob + row * 64 + hid] = bf16_hi_trunc(hv);
                    Xlo[hob + row * 64 + hid] =
                        bf16_rne(hv - trunc_bf16_f32(hv));
                }
        } else {
#pragma unroll
            for (int mt = 0; mt < 2; ++mt)
#pragma unroll
                for (int r = 0; r < 4; ++r) {
                    int row = sh * 32 + mt * 16 + q * 4 + r;
                    int col = hid ^ ((row & 7) << 3);
                    float hv = hv_[mt][r];
                    hbuf[0][row][col] = bf16_hi_trunc(hv);
                    hbuf[1][row][col] = bf16_rne(hv - trunc_bf16_f32(hv));
                }
            __syncthreads();   // writes visible for next step
        }
    }
}

// ---------------- T1 (VALU fp32, hi/lo bf16 I/O) ---------------------------
// T1[br][o][b][m][cl] = sum_n G[br][o][n][m] * X[br][b][n][cl]
__global__ __launch_bounds__(256) void k_t1(
    const short* __restrict__ Xhi, const short* __restrict__ Xlo,
    const float* __restrict__ G,
    short* __restrict__ T1hi, short* __restrict__ T1lo)
{
    const int br = blockIdx.z;
    const int o = blockIdx.y >> 3, b = blockIdx.y & 7;
    const int cl = blockIdx.x * 256 + threadIdx.x;
    const unsigned short* xh = (const unsigned short*)Xhi;
    const unsigned short* xl = (const unsigned short*)Xlo;
    const size_t xb = ((size_t)(br * 8 + b) * 64) * 4096 + cl;
    const float* gp = G + ((size_t)(br * 3 + o) * 64) * 64;
    float acc[64];
#pragma unroll
    for (int mm = 0; mm < 64; ++mm) acc[mm] = 0.f;
#pragma unroll 4
    for (int n = 0; n < 64; ++n) {
        float xv = from_bf16(xh[xb + (size_t)n * 4096]) +
                   from_bf16(xl[xb + (size_t)n * 4096]);
        const float* gr = gp + n * 64;
#pragma unroll
        for (int mm = 0; mm < 64; ++mm) acc[mm] = fmaf(xv, gr[mm], acc[mm]);
    }
    const size_t tb = (((size_t)(br * 3 + o) * 8 + b) * 64) * 4096 + cl;
#pragma unroll
    for (int mm = 0; mm < 64; ++mm) {
        float f = acc[mm];
        T1hi[tb + (size_t)mm * 4096] = bf16_hi_trunc(f);
        T1lo[tb + (size_t)mm * 4096] = bf16_rne(f - trunc_bf16_f32(f));
    }
}

// ---------------- T2 + FC (MFMA) -------------------------------------------
__global__ __launch_bounds__(256) void k_t2fc(
    const short* __restrict__ T1hi, const short* __restrict__ T1lo,
    const short* __restrict__ Wfhi, const short* __restrict__ Wflo,
    const short* __restrict__ Gfhi, const short* __restrict__ Gflo,
    const float* __restrict__ bias, const float* __restrict__ fcW,
    const float* __restrict__ fcb,
    short* __restrict__ Yhi, short* __restrict__ Ylo,
    float* __restrict__ yws, int last)
{
    __shared__ short ldsU[2][3][64][72];   // [plane][d][h][c] (+pad)
    short* u0 = &ldsU[0][0][0][0];
    short* u1 = &ldsU[1][0][0][0];
    const int tid = threadIdx.x, lane = tid & 63;
    const int r16 = lane & 15, q = lane >> 4;
    const int w = __builtin_amdgcn_readfirstlane(tid >> 6);
    const int m = blockIdx.x, b = blockIdx.y, br = blockIdx.z;

    // ---- phase 1: U = T1 @ W (wave w owns c-tile w)
    f32x4 acc1[3][4];
#pragma unroll
    for (int d = 0; d < 3; ++d)
#pragma unroll
        for (int ht = 0; ht < 4; ++ht)
#pragma unroll
            for (int r = 0; r < 4; ++r) acc1[d][ht][r] = 0.f;

    const size_t t1b = (((size_t)br * 3 * 8 + b) * 64 + m) * 4096;
#pragma unroll
    for (int kk = 0; kk < 6; ++kk) {
        const int o = kk >> 1;
        const size_t aoff = t1b + (size_t)o * (8 * 64 * 4096) +
                            (w * 16 + r16) * 64 + (kk & 1) * 32 + q * 8;
        short8 Ah = *(const short8*)(T1hi + aoff);
        short8 Al = *(const short8*)(T1lo + aoff);
#pragma unroll
        for (int d = 0; d < 3; ++d) {
#pragma unroll
            for (int ht = 0; ht < 4; ++ht) {
                const int widx = ((((br * 3 + d) * 4 + ht) * 6 + kk) << 9) + lane * 8;
                short8 Bh = *(const short8*)(Wfhi + widx);
                short8 Bl = *(const short8*)(Wflo + widx);
                acc1[d][ht] = __builtin_amdgcn_mfma_f32_16x16x32_bf16(
                    Ah, Bh, acc1[d][ht], 0, 0, 0);
                acc1[d][ht] = __builtin_amdgcn_mfma_f32_16x16x32_bf16(
                    Ah, Bl, acc1[d][ht], 0, 0, 0);
                acc1[d][ht] = __builtin_amdgcn_mfma_f32_16x16x32_bf16(
                    Al, Bh, acc1[d][ht], 0, 0, 0);
            }
        }
    }
#pragma unroll
    for (int d = 0; d < 3; ++d)
#pragma unroll
        for (int ht = 0; ht < 4; ++ht)
#pragma unroll
            for (int r = 0; r < 4; ++r) {
                float f = acc1[d][ht][r];
                int c = w * 16 + q * 4 + r;
                int h = ht * 16 + r16;
                int ui = (d * 64 + h) * 72 + c;
                u0[ui] = bf16_hi_trunc(f);
                u1[ui] = bf16_rne(f - trunc_bf16_f32(f));
            }
    __syncthreads();

    // ---- phase 2: out = G^T @ U + bias (wave w owns e-tile w)
    f32x4 acc2[4];
#pragma unroll
    for (int ht = 0; ht < 4; ++ht) {
        float bb = bias[br * 64 + ht * 16 + r16];
#pragma unroll
        for (int r = 0; r < 4; ++r) acc2[ht][r] = bb;
    }
#pragma unroll
    for (int kk = 0; kk < 6; ++kk) {
        const int gi = (((br * 4 + w) * 6 + kk) << 9) + lane * 8;
        short8 A2h = *(const short8*)(Gfhi + gi);
        short8 A2l = *(const short8*)(Gflo + gi);
        const int d = kk >> 1, cb = (kk & 1) * 32 + q * 8;
#pragma unroll
        for (int ht = 0; ht < 4; ++ht) {
            const int bi = (d * 64 + ht * 16 + r16) * 72 + cb;
            short8 B2h = *(const short8*)(u0 + bi);
            short8 B2l = *(const short8*)(u1 + bi);
            acc2[ht] = __builtin_amdgcn_mfma_f32_16x16x32_bf16(
                A2h, B2h, acc2[ht], 0, 0, 0);
            acc2[ht] = __builtin_amdgcn_mfma_f32_16x16x32_bf16(
                A2h, B2l, acc2[ht], 0, 0, 0);
            acc2[ht] = __builtin_amdgcn_mfma_f32_16x16x32_bf16(
                A2l, B2h, acc2[ht], 0, 0, 0);
        }
    }

    if (!last) {
        __syncthreads();
        float* ldsO = (float*)u0;   // 16 KB, fits in plane 0
#pragma unroll
        for (int ht = 0; ht < 4; ++ht)
#pragma unroll
            for (int r = 0; r < 4; ++r)
                ldsO[(w * 16 + q * 4 + r) * 64 + ht * 16 + r16] = acc2[ht][r];
        __syncthreads();
        const size_t yb = ((size_t)(br * 8 + b) * 64 + m) * 4096;
        const int i0 = tid * 16;
#pragma unroll
        for (int half = 0; half < 2; ++half) {
            short8 h8, l8;
#pragma unroll
            for (int ii = 0; ii < 8; ++ii) {
                float f = ldsO[i0 + half * 8 + ii];
                h8[ii] = bf16_hi_trunc(f);
                l8[ii] = bf16_rne(f - trunc_bf16_f32(f));
            }
            *(short8*)(Yhi + yb + i0 + half * 8) = h8;
            *(short8*)(Ylo + yb + i0 + half * 8) = l8;
        }
    } else {
        float p[4];
#pragma unroll
        for (int r = 0; r < 4; ++r) {
            p[r] = 0.f;
#pragma unroll
            for (int ht = 0; ht < 4; ++ht)
                p[r] += acc2[ht][r] * fcW[br * 64 + ht * 16 + r16];
        }
#pragma unroll
        for (int off = 1; off < 16; off <<= 1)
#pragma unroll
            for (int r = 0; r < 4; ++r) p[r] += __shfl_xor(p[r], off);
        if (r16 == 0) {
            float fb = fcb[br];
#pragma unroll
            for (int r = 0; r < 4; ++r) {
                int e = w * 16 + q * 4 + r;
                yws[(size_t)br * 32768 + (size_t)b * 4096 + m * 64 + e] =
                    fmaxf(p[r] + fb, 0.f);
            }
        }
    }
}

__global__ __launch_bounds__(256) void k_mean(
    const float* __restrict__ yws, float* __restrict__ out)
{
    int idx = blockIdx.x * 256 + threadIdx.x;
    out[idx] = 0.5f * (yws[idx] + yws[32768 + idx]);
}

extern "C" void kernel_launch(void* const* d_in, const int* in_sizes, int n_in,
                              void* d_out, int out_size, void* d_ws, size_t ws_size,
                              hipStream_t stream)
{
    const float* x   = (const float*)d_in[0];
    const float* G   = (const float*)d_in[1];
    const float* wih = (const float*)d_in[2];
    const float* whh = (const float*)d_in[3];
    const float* bih = (const float*)d_in[4];
    const float* bhh = (const float*)d_in[5];
    const float* W0  = (const float*)d_in[6];
    const float* b0  = (const float*)d_in[7];
    const float* W1  = (const float*)d_in[8];
    const float* b1  = (const float*)d_in[9];
    const float* fcW = (const float*)d_in[10];
    const float* fcb = (const float*)d_in[11];
    float* out = (float*)d_out;

    // ws layout (shorts unless noted). Total ~68.2 MB.
    short* Xhi   = (short*)d_ws;            // 4,194,304
    short* Xlo   = Xhi + 4194304;
    short* T1hi  = Xlo + 4194304;           // 12,582,912
    short* T1lo  = T1hi + 12582912;
    float* yws   = (float*)(T1lo + 12582912);  // 65,536 f32
    short* Wfhi  = (short*)(yws + 65536);   // 147,456
    short* Wflo  = Wfhi + 147456;
    short* Gfhi  = Wflo + 147456;           // 24,576
    short* Gflo  = Gfhi + 24576;
    short* Whfhi = Gflo + 24576;            // 32,768
    short* Whflo = Whfhi + 32768;
    short* Y1hi  = Xhi;                     // reuse (X dead after layer-1 k_t1)
    short* Y1lo  = Xlo;

    k_prep<<<800, 256, 0, stream>>>(G, W0, W1, whh,
                                    Wfhi, Wflo, Gfhi, Gflo, Whfhi, Whflo);
    k_lstm<<<dim3(256, 2), 1024, 0, stream>>>(x, Whfhi, Whflo, wih, bih, bhh,
                                              Xhi, Xlo);

    // layer 1
    k_t1<<<dim3(16, 24, 2), 256, 0, stream>>>(Xhi, Xlo, G, T1hi, T1lo);
    k_t2fc<<<dim3(64, 8, 2), 256, 0, stream>>>(T1hi, T1lo, Wfhi, Wflo,
                                               Gfhi, Gflo, b0, fcW, fcb,
                                               Y1hi, Y1lo, yws, 0);
    // layer 2
    k_t1<<<dim3(16, 24, 2), 256, 0, stream>>>(Y1hi, Y1lo, G, T1hi, T1lo);
    k_t2fc<<<dim3(64, 8, 2), 256, 0, stream>>>(T1hi, T1lo,
                                               Wfhi + 73728, Wflo + 73728,
                                               Gfhi, Gflo, b1, fcW, fcb,
                                               (short*)nullptr, (short*)nullptr,
                                               yws, 1);
    k_mean<<<128, 256, 0, stream>>>(yws, out);
}

// Round 6
// 320.178 us; speedup vs baseline: 1.2694x; 1.0248x over previous
//
#include <hip/hip_runtime.h>
#include <hip/hip_bf16.h>

// M=2 branches, K=3 diffusion, N=64, I=1, H=64, B=8, T=12

typedef __attribute__((ext_vector_type(8))) short short8;   // 8 bf16 (4 VGPRs)
typedef __attribute__((ext_vector_type(4))) float f32x4;    // 4 fp32

__device__ __forceinline__ short bf16_hi_trunc(float f) {
    union { float f; unsigned u; } v; v.f = f;
    return (short)(v.u >> 16);
}
__device__ __forceinline__ float trunc_bf16_f32(float f) {
    union { float f; unsigned u; } v; v.f = f;
    v.u &= 0xFFFF0000u;
    return v.f;
}
__device__ __forceinline__ short bf16_rne(float f) {
    union { float f; unsigned u; } v; v.f = f;
    unsigned r = ((v.u >> 16) & 1u) + 0x7FFFu;
    return (short)((v.u + r) >> 16);
}
__device__ __forceinline__ float from_bf16(unsigned short s) {
    union { unsigned u; float f; } v; v.u = ((unsigned)s) << 16;
    return v.f;
}
__device__ __forceinline__ float sigmoidf_(float x) {
    float e = __builtin_amdgcn_exp2f(x * -1.442695041f);
    return __builtin_amdgcn_rcpf(1.f + e);
}
__device__ __forceinline__ float tanhf_(float x) {
    float e2 = __builtin_amdgcn_exp2f(x * 2.885390082f);
    return fmaf(-2.f, __builtin_amdgcn_rcpf(e2 + 1.f), 1.f);
}

// ---------------- prep: pack W, G^T, Whh into MFMA fragment order ----------
// Wf [layer][br][d][ht][kk][lane][8] : 147456/plane
// Gf [br][et][kk][lane][8]           : 24576/plane
// Whf[br][kt][gg][w][lane][8]        : 32768/plane  (B[k][gate] of WhhT)
__global__ __launch_bounds__(256) void k_prep(
    const float* __restrict__ G, const float* __restrict__ W0,
    const float* __restrict__ W1, const float* __restrict__ whh,
    short* __restrict__ Wfhi, short* __restrict__ Wflo,
    short* __restrict__ Gfhi, short* __restrict__ Gflo,
    short* __restrict__ Whfhi, short* __restrict__ Whflo)
{
    int idx = blockIdx.x * 256 + threadIdx.x;
    float v; short *dh, *dl; int didx;
    if (idx < 147456) {
        int j = idx & 7, lane = (idx >> 3) & 63, kk = (idx >> 9) % 6;
        int t2 = idx / 3072;
        int ht = t2 & 3; t2 >>= 2;
        int d = t2 % 3; t2 /= 3;
        int br = t2 & 1, layer = t2 >> 1;
        int k = kk * 32 + ((lane >> 4) << 3) + j;
        int o = k >> 6, l = k & 63, h = ht * 16 + (lane & 15);
        const float* Wp = layer ? W1 : W0;
        v = Wp[((size_t)br * 576 + (o * 3 + d) * 64 + l) * 64 + h];
        dh = Wfhi; dl = Wflo; didx = idx;
    } else if (idx < 172032) {
        int i2 = idx - 147456;
        int j = i2 & 7, lane = (i2 >> 3) & 63, kk = (i2 >> 9) % 6;
        int t2 = i2 / 3072;
        int et = t2 & 3, br = t2 >> 2;
        int k = kk * 32 + ((lane >> 4) << 3) + j;
        int d = k >> 6, c = k & 63, e = et * 16 + (lane & 15);
        v = G[(((size_t)br * 3 + d) * 64 + c) * 64 + e];
        dh = Gfhi; dl = Gflo; didx = i2;
    } else {
        int i3 = idx - 172032;
        int j = i3 & 7, lane = (i3 >> 3) & 63;
        int w = (i3 >> 9) & 3, gg = (i3 >> 11) & 3;
        int kt = (i3 >> 13) & 1, br = (i3 >> 14) & 1;
        int gate = gg * 64 + w * 16 + (lane & 15);
        int k = kt * 32 + ((lane >> 4) << 3) + j;
        v = whh[((size_t)br * 256 + gate) * 64 + k];
        dh = Whfhi; dl = Whflo; didx = i3;
    }
    dh[didx] = bf16_hi_trunc(v);
    dl[didx] = bf16_rne(v - trunc_bf16_f32(v));
}

// ---------------- LSTM: 128 seqs/block, dbuf hbuf (1 barrier/step), --------
// ---------------- x prefetch, LDS-resident weights -------------------------
__global__ __launch_bounds__(1024, 4) void k_lstm(
    const float* __restrict__ x, const short* __restrict__ Whfhi,
    const short* __restrict__ Whflo, const float* __restrict__ wih,
    const float* __restrict__ bih, const float* __restrict__ bhh,
    short* __restrict__ Xhi, short* __restrict__ Xlo)
{
    __shared__ short wlds[2][16384];        // weights, 64 KB
    __shared__ short hbuf[2][2][128][64];   // [dbuf][plane][row][col], 64 KB
    const int tid = threadIdx.x;
    const int lane = tid & 63;
    const int ww = __builtin_amdgcn_readfirstlane(tid >> 6);  // 0..15
    const int sh = ww >> 2;
    const int w = ww & 3;
    const int q = lane >> 4;
    const int r16 = lane & 15;
    const int br = blockIdx.y;
    const int b = blockIdx.x >> 5, o2 = blockIdx.x & 31;

    // stage Whh fragment tables into LDS (one-time, coalesced)
    {
        const short* s0 = Whfhi + (size_t)br * 16384 + tid * 16;
        const short* s1 = Whflo + (size_t)br * 16384 + tid * 16;
        *(short8*)&wlds[0][tid * 16] = *(const short8*)s0;
        *(short8*)&wlds[0][tid * 16 + 8] = *(const short8*)(s0 + 8);
        *(short8*)&wlds[1][tid * 16] = *(const short8*)s1;
        *(short8*)&wlds[1][tid * 16 + 8] = *(const short8*)(s1 + 8);
    }

    float wihv[4], biasv[4];
#pragma unroll
    for (int gg = 0; gg < 4; ++gg) {
        const int gate = gg * 64 + w * 16 + r16;
        wihv[gg] = wih[br * 256 + gate];
        biasv[gg] = bih[br * 256 + gate] + bhh[br * 256 + gate];
    }

    float cst[2][4];
#pragma unroll
    for (int mt = 0; mt < 2; ++mt)
#pragma unroll
        for (int r = 0; r < 4; ++r) cst[mt][r] = 0.f;

    const float* xb = x + (size_t)b * 12 * 4096 + o2 * 128 + sh * 32;
    const size_t hob = (size_t)(br * 8 + b) * 262144 + (size_t)o2 * 8192;
    const int hid = w * 16 + r16;

    // prefetch x for t=0
    float4 nx0 = *(const float4*)(xb + q * 4);
    float4 nx1 = *(const float4*)(xb + 16 + q * 4);

    __syncthreads();   // weights staged

    for (int t = 0; t < 12; ++t) {
        float4 xv0 = nx0, xv1 = nx1;
        if (t < 11) {   // prefetch next step's x (overlaps MFMA + activations)
            const float* xn = xb + (size_t)(t + 1) * 4096;
            nx0 = *(const float4*)(xn + q * 4);
            nx1 = *(const float4*)(xn + 16 + q * 4);
        }
        float xm[2][4] = {{xv0.x, xv0.y, xv0.z, xv0.w},
                          {xv1.x, xv1.y, xv1.z, xv1.w}};
        f32x4 acc[2][4];   // [mt][gg]
#pragma unroll
        for (int mt = 0; mt < 2; ++mt)
#pragma unroll
            for (int r = 0; r < 4; ++r)
#pragma unroll
                for (int gg = 0; gg < 4; ++gg)
                    acc[mt][gg][r] = fmaf(xm[mt][r], wihv[gg], biasv[gg]);

        if (t > 0) {
            const short* hb0 = &hbuf[t & 1][0][0][0];
#pragma unroll 1
            for (int kt = 0; kt < 2; ++kt) {
                short8 Bh[4], Bl[4];
#pragma unroll
                for (int gg = 0; gg < 4; ++gg) {
                    const int bidx = (((kt * 4 + gg) * 4 + w) * 64 + lane) * 8;
                    Bh[gg] = *(const short8*)&wlds[0][bidx];
                    Bl[gg] = *(const short8*)&wlds[1][bidx];
                }
                short8 Ah[2], Al[2];
#pragma unroll
                for (int mt = 0; mt < 2; ++mt) {
                    const int row = sh * 32 + mt * 16 + r16;
                    const int col = (kt * 32 + q * 8) ^ ((r16 & 7) << 3);
                    Ah[mt] = *(const short8*)&hb0[row * 64 + col];
                    Al[mt] = *(const short8*)&hb0[8192 + row * 64 + col];
                }
#pragma unroll
                for (int mt = 0; mt < 2; ++mt)
#pragma unroll
                    for (int gg = 0; gg < 4; ++gg) {
                        acc[mt][gg] = __builtin_amdgcn_mfma_f32_16x16x32_bf16(
                            Ah[mt], Bh[gg], acc[mt][gg], 0, 0, 0);
                        acc[mt][gg] = __builtin_amdgcn_mfma_f32_16x16x32_bf16(
                            Ah[mt], Bl[gg], acc[mt][gg], 0, 0, 0);
                        acc[mt][gg] = __builtin_amdgcn_mfma_f32_16x16x32_bf16(
                            Al[mt], Bh[gg], acc[mt][gg], 0, 0, 0);
                    }
            }
        }
        // activations (torch gate order i,f,g,o)
        float hv_[2][4];
#pragma unroll
        for (int mt = 0; mt < 2; ++mt) {
#pragma unroll
            for (int r = 0; r < 4; ++r) {
                float ig = sigmoidf_(acc[mt][0][r]);
                float fg = sigmoidf_(acc[mt][1][r]);
                float gt = tanhf_(acc[mt][2][r]);
                float og = sigmoidf_(acc[mt][3][r]);
                float c = fmaf(fg, cst[mt][r], ig * gt);
                cst[mt][r] = c;
                hv_[mt][r] = og * tanhf_(c);
            }
        }
        if (t == 11) {
#pragma unroll
            for (int mt = 0; mt < 2; ++mt)
#pragma unroll
                for (int r = 0; r < 4; ++r) {
                    int row = sh * 32 + mt * 16 + q * 4 + r;
                    float hv = hv_[mt][r];
                    Xhi[hob + row * 64 + hid] = bf16_hi_trunc(hv);
                    Xlo[hob + row * 64 + hid] =
                        bf16_rne(hv - trunc_bf16_f32(hv));
                }
        } else {
            short* hw0 = &hbuf[(t + 1) & 1][0][0][0];
#pragma unroll
            for (int mt = 0; mt < 2; ++mt)
#pragma unroll
                for (int r = 0; r < 4; ++r) {
                    int row = sh * 32 + mt * 16 + q * 4 + r;
                    int col = hid ^ ((row & 7) << 3);
                    float hv = hv_[mt][r];
                    hw0[row * 64 + col] = bf16_hi_trunc(hv);
                    hw0[8192 + row * 64 + col] =
                        bf16_rne(hv - trunc_bf16_f32(hv));
                }
            __syncthreads();   // single barrier per step (dbuf)
        }
    }
}

// ---------------- T1 (VALU fp32, hi/lo bf16 I/O) ---------------------------
// T1[br][o][b][m][cl] = sum_n G[br][o][n][m] * X[br][b][n][cl]
__global__ __launch_bounds__(256) void k_t1(
    const short* __restrict__ Xhi, const short* __restrict__ Xlo,
    const float* __restrict__ G,
    short* __restrict__ T1hi, short* __restrict__ T1lo)
{
    const int br = blockIdx.z;
    const int o = blockIdx.y >> 3, b = blockIdx.y & 7;
    const int cl = blockIdx.x * 256 + threadIdx.x;
    const unsigned short* xh = (const unsigned short*)Xhi;
    const unsigned short* xl = (const unsigned short*)Xlo;
    const size_t xb = ((size_t)(br * 8 + b) * 64) * 4096 + cl;
    const float* gp = G + ((size_t)(br * 3 + o) * 64) * 64;
    float acc[64];
#pragma unroll
    for (int mm = 0; mm < 64; ++mm) acc[mm] = 0.f;
#pragma unroll 4
    for (int n = 0; n < 64; ++n) {
        float xv = from_bf16(xh[xb + (size_t)n * 4096]) +
                   from_bf16(xl[xb + (size_t)n * 4096]);
        const float* gr = gp + n * 64;
#pragma unroll
        for (int mm = 0; mm < 64; ++mm) acc[mm] = fmaf(xv, gr[mm], acc[mm]);
    }
    const size_t tb = (((size_t)(br * 3 + o) * 8 + b) * 64) * 4096 + cl;
#pragma unroll
    for (int mm = 0; mm < 64; ++mm) {
        float f = acc[mm];
        T1hi[tb + (size_t)mm * 4096] = bf16_hi_trunc(f);
        T1lo[tb + (size_t)mm * 4096] = bf16_rne(f - trunc_bf16_f32(f));
    }
}

// ---------------- T2 + FC (MFMA), LDS-staged T1, wave-split W --------------
// Per (br,b,m): U[d][c][h] = sum_{o,l} T1[o][c][l] W[(o,d)l][h]   (phase 1)
//              out[e][h]  = bias[h] + sum_{d,c} G[d][c][e] U[d][c][h] (ph 2)
__global__ __launch_bounds__(256) void k_t2fc(
    const short* __restrict__ T1hi, const short* __restrict__ T1lo,
    const short* __restrict__ Wfhi, const short* __restrict__ Wflo,
    const short* __restrict__ Gfhi, const short* __restrict__ Gflo,
    const float* __restrict__ bias, const float* __restrict__ fcW,
    const float* __restrict__ fcb,
    short* __restrict__ Yhi, short* __restrict__ Ylo,
    float* __restrict__ yws, int last)
{
    // region reuse: stage T1 [6][4096] (24576 sh) -> U [2][3][64][72] (27648 sh)
    __shared__ short lds[27648];
    const int tid = threadIdx.x, lane = tid & 63;
    const int r16 = lane & 15, q = lane >> 4;
    const int w = __builtin_amdgcn_readfirstlane(tid >> 6);
    const int m = blockIdx.x, b = blockIdx.y, br = blockIdx.z;

    // ---- stage T1 slice (3 o x 2 plane x 4096) into LDS, XOR-swizzled ----
    const size_t t1b = (((size_t)br * 24 + b) * 64 + m) * 4096;
#pragma unroll
    for (int it = 0; it < 12; ++it) {
        int flat = it * 2048 + tid * 8;
        int p2 = flat >> 12;            // o*2 + plane
        int li = flat & 4095;           // c*64 + l
        int c = li >> 6, l = li & 63;
        const short* src = ((p2 & 1) ? T1lo : T1hi) + t1b +
                           (size_t)(p2 >> 1) * 2097152 + li;
        int dst = p2 * 4096 + c * 64 + (l ^ ((c & 7) << 3));
        *(short8*)&lds[dst] = *(const short8*)src;
    }
    __syncthreads();

    // ---- phase 1: U = T1 @ W. Wave w owns combos {w*3..w*3+2} (d*4+ht),
    //      all 4 c-tiles. W-frag loads: 36/wave (no cross-wave redundancy).
    f32x4 acc1[3][4];   // [i][ct]
#pragma unroll
    for (int i = 0; i < 3; ++i)
#pragma unroll
        for (int ct = 0; ct < 4; ++ct)
#pragma unroll
            for (int r = 0; r < 4; ++r) acc1[i][ct][r] = 0.f;

#pragma unroll
    for (int kk = 0; kk < 6; ++kk) {
        const int o = kk >> 1;
        short8 Wh[3], Wl[3];
#pragma unroll
        for (int i = 0; i < 3; ++i) {
            const int combo = w * 3 + i;          // d*4 + ht
            const int d = combo >> 2, ht = combo & 3;
            const int widx = ((((br * 3 + d) * 4 + ht) * 6 + kk) << 9) + lane * 8;
            Wh[i] = *(const short8*)(Wfhi + widx);
            Wl[i] = *(const short8*)(Wflo + widx);
        }
        short8 Ah[4], Al[4];
#pragma unroll
        for (int ct = 0; ct < 4; ++ct) {
            const int c = ct * 16 + r16;
            const int lbase = ((kk & 1) * 32 + q * 8) ^ ((r16 & 7) << 3);
            Ah[ct] = *(const short8*)&lds[(o * 2 + 0) * 4096 + c * 64 + lbase];
            Al[ct] = *(const short8*)&lds[(o * 2 + 1) * 4096 + c * 64 + lbase];
        }
#pragma unroll
        for (int i = 0; i < 3; ++i)
#pragma unroll
            for (int ct = 0; ct < 4; ++ct) {
                acc1[i][ct] = __builtin_amdgcn_mfma_f32_16x16x32_bf16(
                    Ah[ct], Wh[i], acc1[i][ct], 0, 0, 0);
                acc1[i][ct] = __builtin_amdgcn_mfma_f32_16x16x32_bf16(
                    Ah[ct], Wl[i], acc1[i][ct], 0, 0, 0);
                acc1[i][ct] = __builtin_amdgcn_mfma_f32_16x16x32_bf16(
                    Al[ct], Wh[i], acc1[i][ct], 0, 0, 0);
            }
    }
    __syncthreads();   // T1-LDS reads done; region becomes U

    short* u0 = lds;
    short* u1 = lds + 13824;   // 3*64*72
#pragma unroll
    for (int i = 0; i < 3; ++i) {
        const int combo = w * 3 + i;
        const int d = combo >> 2, ht = combo & 3;
        const int h = ht * 16 + r16;
#pragma unroll
        for (int ct = 0; ct < 4; ++ct)
#pragma unroll
            for (int r = 0; r < 4; ++r) {
                float f = acc1[i][ct][r];
                int c = ct * 16 + q * 4 + r;
                int ui = (d * 64 + h) * 72 + c;
                u0[ui] = bf16_hi_trunc(f);
                u1[ui] = bf16_rne(f - trunc_bf16_f32(f));
            }
    }
    __syncthreads();

    // ---- phase 2: out = G^T @ U + bias (wave w owns e-tile w)
    f32x4 acc2[4];
#pragma unroll
    for (int ht = 0; ht < 4; ++ht) {
        float bb = bias[br * 64 + ht * 16 + r16];
#pragma unroll
        for (int r = 0; r < 4; ++r) acc2[ht][r] = bb;
    }
#pragma unroll
    for (int kk = 0; kk < 6; ++kk) {
        const int gi = (((br * 4 + w) * 6 + kk) << 9) + lane * 8;
        short8 A2h = *(const short8*)(Gfhi + gi);
        short8 A2l = *(const short8*)(Gflo + gi);
        const int d = kk >> 1, cb = (kk & 1) * 32 + q * 8;
#pragma unroll
        for (int ht = 0; ht < 4; ++ht) {
            const int bi = (d * 64 + ht * 16 + r16) * 72 + cb;
            short8 B2h = *(const short8*)(u0 + bi);
            short8 B2l = *(const short8*)(u1 + bi);
            acc2[ht] = __builtin_amdgcn_mfma_f32_16x16x32_bf16(
                A2h, B2h, acc2[ht], 0, 0, 0);
            acc2[ht] = __builtin_amdgcn_mfma_f32_16x16x32_bf16(
                A2h, B2l, acc2[ht], 0, 0, 0);
            acc2[ht] = __builtin_amdgcn_mfma_f32_16x16x32_bf16(
                A2l, B2h, acc2[ht], 0, 0, 0);
        }
    }

    if (!last) {
        __syncthreads();
        float* ldsO = (float*)lds;   // 16 KB
#pragma unroll
        for (int ht = 0; ht < 4; ++ht)
#pragma unroll
            for (int r = 0; r < 4; ++r)
                ldsO[(w * 16 + q * 4 + r) * 64 + ht * 16 + r16] = acc2[ht][r];
        __syncthreads();
        const size_t yb = ((size_t)(br * 8 + b) * 64 + m) * 4096;
        const int i0 = tid * 16;
#pragma unroll
        for (int half = 0; half < 2; ++half) {
            short8 h8, l8;
#pragma unroll
            for (int ii = 0; ii < 8; ++ii) {
                float f = ldsO[i0 + half * 8 + ii];
                h8[ii] = bf16_hi_trunc(f);
                l8[ii] = bf16_rne(f - trunc_bf16_f32(f));
            }
            *(short8*)(Yhi + yb + i0 + half * 8) = h8;
            *(short8*)(Ylo + yb + i0 + half * 8) = l8;
        }
    } else {
        float p[4];
#pragma unroll
        for (int r = 0; r < 4; ++r) {
            p[r] = 0.f;
#pragma unroll
            for (int ht = 0; ht < 4; ++ht)
                p[r] += acc2[ht][r] * fcW[br * 64 + ht * 16 + r16];
        }
#pragma unroll
        for (int off = 1; off < 16; off <<= 1)
#pragma unroll
            for (int r = 0; r < 4; ++r) p[r] += __shfl_xor(p[r], off);
        if (r16 == 0) {
            float fb = fcb[br];
#pragma unroll
            for (int r = 0; r < 4; ++r) {
                int e = w * 16 + q * 4 + r;
                yws[(size_t)br * 32768 + (size_t)b * 4096 + m * 64 + e] =
                    fmaxf(p[r] + fb, 0.f);
            }
        }
    }
}

__global__ __launch_bounds__(256) void k_mean(
    const float* __restrict__ yws, float* __restrict__ out)
{
    int idx = blockIdx.x * 256 + threadIdx.x;
    out[idx] = 0.5f * (yws[idx] + yws[32768 + idx]);
}

extern "C" void kernel_launch(void* const* d_in, const int* in_sizes, int n_in,
                              void* d_out, int out_size, void* d_ws, size_t ws_size,
                              hipStream_t stream)
{
    const float* x   = (const float*)d_in[0];
    const float* G   = (const float*)d_in[1];
    const float* wih = (const float*)d_in[2];
    const float* whh = (const float*)d_in[3];
    const float* bih = (const float*)d_in[4];
    const float* bhh = (const float*)d_in[5];
    const float* W0  = (const float*)d_in[6];
    const float* b0  = (const float*)d_in[7];
    const float* W1  = (const float*)d_in[8];
    const float* b1  = (const float*)d_in[9];
    const float* fcW = (const float*)d_in[10];
    const float* fcb = (const float*)d_in[11];
    float* out = (float*)d_out;

    // ws layout (shorts unless noted). Total ~68.2 MB.
    short* Xhi   = (short*)d_ws;            // 4,194,304
    short* Xlo   = Xhi + 4194304;
    short* T1hi  = Xlo + 4194304;           // 12,582,912
    short* T1lo  = T1hi + 12582912;
    float* yws   = (float*)(T1lo + 12582912);  // 65,536 f32
    short* Wfhi  = (short*)(yws + 65536);   // 147,456
    short* Wflo  = Wfhi + 147456;
    short* Gfhi  = Wflo + 147456;           // 24,576
    short* Gflo  = Gfhi + 24576;
    short* Whfhi = Gflo + 24576;            // 32,768
    short* Whflo = Whfhi + 32768;
    short* Y1hi  = Xhi;                     // reuse (X dead after layer-1 k_t1)
    short* Y1lo  = Xlo;

    k_prep<<<800, 256, 0, stream>>>(G, W0, W1, whh,
                                    Wfhi, Wflo, Gfhi, Gflo, Whfhi, Whflo);
    k_lstm<<<dim3(256, 2), 1024, 0, stream>>>(x, Whfhi, Whflo, wih, bih, bhh,
                                              Xhi, Xlo);

    // layer 1
    k_t1<<<dim3(16, 24, 2), 256, 0, stream>>>(Xhi, Xlo, G, T1hi, T1lo);
    k_t2fc<<<dim3(64, 8, 2), 256, 0, stream>>>(T1hi, T1lo, Wfhi, Wflo,
                                               Gfhi, Gflo, b0, fcW, fcb,
                                               Y1hi, Y1lo, yws, 0);
    // layer 2
    k_t1<<<dim3(16, 24, 2), 256, 0, stream>>>(Y1hi, Y1lo, G, T1hi, T1lo);
    k_t2fc<<<dim3(64, 8, 2), 256, 0, stream>>>(T1hi, T1lo,
                                               Wfhi + 73728, Wflo + 73728,
                                               Gfhi, Gflo, b1, fcW, fcb,
                                               (short*)nullptr, (short*)nullptr,
                                               yws, 1);
    k_mean<<<128, 256, 0, stream>>>(yws, out);
}

// Round 7
// 304.578 us; speedup vs baseline: 1.3344x; 1.0512x over previous
//
#include <hip/hip_runtime.h>
#include <hip/hip_bf16.h>

// M=2 branches, K=3 diffusion, N=64, I=1, H=64, B=8, T=12

typedef __attribute__((ext_vector_type(8))) short short8;   // 8 bf16 (4 VGPRs)
typedef __attribute__((ext_vector_type(4))) float f32x4;    // 4 fp32

__device__ __forceinline__ short bf16_hi_trunc(float f) {
    union { float f; unsigned u; } v; v.f = f;
    return (short)(v.u >> 16);
}
__device__ __forceinline__ float trunc_bf16_f32(float f) {
    union { float f; unsigned u; } v; v.f = f;
    v.u &= 0xFFFF0000u;
    return v.f;
}
__device__ __forceinline__ short bf16_rne(float f) {
    union { float f; unsigned u; } v; v.f = f;
    unsigned r = ((v.u >> 16) & 1u) + 0x7FFFu;
    return (short)((v.u + r) >> 16);
}
__device__ __forceinline__ float from_bf16(unsigned short s) {
    union { unsigned u; float f; } v; v.u = ((unsigned)s) << 16;
    return v.f;
}
__device__ __forceinline__ float sigmoidf_(float x) {
    float e = __builtin_amdgcn_exp2f(x * -1.442695041f);
    return __builtin_amdgcn_rcpf(1.f + e);
}
__device__ __forceinline__ float tanhf_(float x) {
    float e2 = __builtin_amdgcn_exp2f(x * 2.885390082f);
    return fmaf(-2.f, __builtin_amdgcn_rcpf(e2 + 1.f), 1.f);
}

// ---------------- prep: pack W, G^T, Whh into MFMA fragment order ----------
// Wf [layer][br][d][ht][kk][lane][8] : 147456/plane
// Gf [br][et][kk][lane][8]           : 24576/plane
// Whf[br][kt][gg][w][lane][8]        : 32768/plane  (B[k][gate] of WhhT)
__global__ __launch_bounds__(256) void k_prep(
    const float* __restrict__ G, const float* __restrict__ W0,
    const float* __restrict__ W1, const float* __restrict__ whh,
    short* __restrict__ Wfhi, short* __restrict__ Wflo,
    short* __restrict__ Gfhi, short* __restrict__ Gflo,
    short* __restrict__ Whfhi, short* __restrict__ Whflo)
{
    int idx = blockIdx.x * 256 + threadIdx.x;
    float v; short *dh, *dl; int didx;
    if (idx < 147456) {
        int j = idx & 7, lane = (idx >> 3) & 63, kk = (idx >> 9) % 6;
        int t2 = idx / 3072;
        int ht = t2 & 3; t2 >>= 2;
        int d = t2 % 3; t2 /= 3;
        int br = t2 & 1, layer = t2 >> 1;
        int k = kk * 32 + ((lane >> 4) << 3) + j;
        int o = k >> 6, l = k & 63, h = ht * 16 + (lane & 15);
        const float* Wp = layer ? W1 : W0;
        v = Wp[((size_t)br * 576 + (o * 3 + d) * 64 + l) * 64 + h];
        dh = Wfhi; dl = Wflo; didx = idx;
    } else if (idx < 172032) {
        int i2 = idx - 147456;
        int j = i2 & 7, lane = (i2 >> 3) & 63, kk = (i2 >> 9) % 6;
        int t2 = i2 / 3072;
        int et = t2 & 3, br = t2 >> 2;
        int k = kk * 32 + ((lane >> 4) << 3) + j;
        int d = k >> 6, c = k & 63, e = et * 16 + (lane & 15);
        v = G[(((size_t)br * 3 + d) * 64 + c) * 64 + e];
        dh = Gfhi; dl = Gflo; didx = i2;
    } else {
        int i3 = idx - 172032;
        int j = i3 & 7, lane = (i3 >> 3) & 63;
        int w = (i3 >> 9) & 3, gg = (i3 >> 11) & 3;
        int kt = (i3 >> 13) & 1, br = (i3 >> 14) & 1;
        int gate = gg * 64 + w * 16 + (lane & 15);
        int k = kt * 32 + ((lane >> 4) << 3) + j;
        v = whh[((size_t)br * 256 + gate) * 64 + k];
        dh = Whfhi; dl = Whflo; didx = i3;
    }
    dh[didx] = bf16_hi_trunc(v);
    dl[didx] = bf16_rne(v - trunc_bf16_f32(v));
}

// ---------------- LSTM v4: 16 seqs/block, 4 waves, register weights --------
// Block = (br, b, o, dg): seqs = dg*16..+15 of node-pair (o,d). Wave w owns
// gate cols {gg*64 + w*16 .. +15}. B-frags register-resident (64 VGPR),
// loaded once from the packed Whf table. hbuf 8 KB dbuf, 1 barrier/step.
__global__ __launch_bounds__(256, 4) void k_lstm(
    const float* __restrict__ x, const short* __restrict__ Whfhi,
    const short* __restrict__ Whflo, const float* __restrict__ wih,
    const float* __restrict__ bih, const float* __restrict__ bhh,
    short* __restrict__ Xhi, short* __restrict__ Xlo)
{
    __shared__ short hbuf[2][2][16][64];   // [dbuf][plane][seq][hid^swz] 8 KB
    const int tid = threadIdx.x;
    const int lane = tid & 63;
    const int w = __builtin_amdgcn_readfirstlane(tid >> 6);   // gate slice 0..3
    const int q = lane >> 4, r16 = lane & 15;
    const int br = blockIdx.y;
    const int bx = blockIdx.x;
    const int dg = bx & 3, o = (bx >> 2) & 63, b = bx >> 8;

    // weight-stationary B fragments (hi/lo), statically indexed -> registers
    short8 Bh[2][4], Bl[2][4];
    {
        const short* wbh = Whfhi + (size_t)br * 16384;
        const short* wbl = Whflo + (size_t)br * 16384;
#pragma unroll
        for (int kt = 0; kt < 2; ++kt)
#pragma unroll
            for (int gg = 0; gg < 4; ++gg) {
                const int bidx = (((kt * 4 + gg) * 4 + w) * 64 + lane) * 8;
                Bh[kt][gg] = *(const short8*)(wbh + bidx);
                Bl[kt][gg] = *(const short8*)(wbl + bidx);
            }
    }

    float wihv[4], biasv[4];
#pragma unroll
    for (int gg = 0; gg < 4; ++gg) {
        const int gate = gg * 64 + w * 16 + r16;
        wihv[gg] = wih[br * 256 + gate];
        biasv[gg] = bih[br * 256 + gate] + bhh[br * 256 + gate];
    }

    float cst[4] = {0.f, 0.f, 0.f, 0.f};
    const float* xb = x + (size_t)b * 12 * 4096 + o * 64 + dg * 16;
    const size_t hob = ((size_t)(br * 8 + b) * 64 + o) * 4096 + dg * 1024;
    const int hid = w * 16 + r16;

    for (int t = 0; t < 12; ++t) {
        f32x4 acc[4];   // [gg]
        float4 xv = *(const float4*)(xb + (size_t)t * 4096 + q * 4);
        float xm[4] = {xv.x, xv.y, xv.z, xv.w};
#pragma unroll
        for (int r = 0; r < 4; ++r)
#pragma unroll
            for (int gg = 0; gg < 4; ++gg)
                acc[gg][r] = fmaf(xm[r], wihv[gg], biasv[gg]);

        if (t > 0) {
            const short* hb0 = &hbuf[t & 1][0][0][0];
#pragma unroll
            for (int kt = 0; kt < 2; ++kt) {
                const int col = (kt * 32 + q * 8) ^ ((r16 & 7) << 3);
                short8 Ah = *(const short8*)&hb0[r16 * 64 + col];
                short8 Al = *(const short8*)&hb0[1024 + r16 * 64 + col];
#pragma unroll
                for (int gg = 0; gg < 4; ++gg) {
                    acc[gg] = __builtin_amdgcn_mfma_f32_16x16x32_bf16(
                        Ah, Bh[kt][gg], acc[gg], 0, 0, 0);
                    acc[gg] = __builtin_amdgcn_mfma_f32_16x16x32_bf16(
                        Ah, Bl[kt][gg], acc[gg], 0, 0, 0);
                    acc[gg] = __builtin_amdgcn_mfma_f32_16x16x32_bf16(
                        Al, Bh[kt][gg], acc[gg], 0, 0, 0);
                }
            }
        }
        // activations (torch gate order i,f,g,o); lane owns seq=q*4+r, hid
        float hv_[4];
#pragma unroll
        for (int r = 0; r < 4; ++r) {
            float ig = sigmoidf_(acc[0][r]);
            float fg = sigmoidf_(acc[1][r]);
            float gt = tanhf_(acc[2][r]);
            float og = sigmoidf_(acc[3][r]);
            float c = fmaf(fg, cst[r], ig * gt);
            cst[r] = c;
            hv_[r] = og * tanhf_(c);
        }
        if (t == 11) {
#pragma unroll
            for (int r = 0; r < 4; ++r) {
                int seq = q * 4 + r;
                float hv = hv_[r];
                Xhi[hob + seq * 64 + hid] = bf16_hi_trunc(hv);
                Xlo[hob + seq * 64 + hid] = bf16_rne(hv - trunc_bf16_f32(hv));
            }
        } else {
            short* hw0 = &hbuf[(t + 1) & 1][0][0][0];
#pragma unroll
            for (int r = 0; r < 4; ++r) {
                int seq = q * 4 + r;
                int col = hid ^ ((seq & 7) << 3);
                float hv = hv_[r];
                hw0[seq * 64 + col] = bf16_hi_trunc(hv);
                hw0[1024 + seq * 64 + col] = bf16_rne(hv - trunc_bf16_f32(hv));
            }
            __syncthreads();   // single barrier per step (dbuf)
        }
    }
}

// ---------------- T1 (VALU fp32, hi/lo bf16 I/O) ---------------------------
// T1[br][o][b][m][cl] = sum_n G[br][o][n][m] * X[br][b][n][cl]
__global__ __launch_bounds__(256) void k_t1(
    const short* __restrict__ Xhi, const short* __restrict__ Xlo,
    const float* __restrict__ G,
    short* __restrict__ T1hi, short* __restrict__ T1lo)
{
    const int br = blockIdx.z;
    const int o = blockIdx.y >> 3, b = blockIdx.y & 7;
    const int cl = blockIdx.x * 256 + threadIdx.x;
    const unsigned short* xh = (const unsigned short*)Xhi;
    const unsigned short* xl = (const unsigned short*)Xlo;
    const size_t xb = ((size_t)(br * 8 + b) * 64) * 4096 + cl;
    const float* gp = G + ((size_t)(br * 3 + o) * 64) * 64;
    float acc[64];
#pragma unroll
    for (int mm = 0; mm < 64; ++mm) acc[mm] = 0.f;
#pragma unroll 4
    for (int n = 0; n < 64; ++n) {
        float xv = from_bf16(xh[xb + (size_t)n * 4096]) +
                   from_bf16(xl[xb + (size_t)n * 4096]);
        const float* gr = gp + n * 64;
#pragma unroll
        for (int mm = 0; mm < 64; ++mm) acc[mm] = fmaf(xv, gr[mm], acc[mm]);
    }
    const size_t tb = (((size_t)(br * 3 + o) * 8 + b) * 64) * 4096 + cl;
#pragma unroll
    for (int mm = 0; mm < 64; ++mm) {
        float f = acc[mm];
        T1hi[tb + (size_t)mm * 4096] = bf16_hi_trunc(f);
        T1lo[tb + (size_t)mm * 4096] = bf16_rne(f - trunc_bf16_f32(f));
    }
}

// ---------------- T2 + FC (MFMA), LDS-staged T1, wave-split W --------------
// Per (br,b,m): U[d][c][h] = sum_{o,l} T1[o][c][l] W[(o,d)l][h]   (phase 1)
//              out[e][h]  = bias[h] + sum_{d,c} G[d][c][e] U[d][c][h] (ph 2)
__global__ __launch_bounds__(256) void k_t2fc(
    const short* __restrict__ T1hi, const short* __restrict__ T1lo,
    const short* __restrict__ Wfhi, const short* __restrict__ Wflo,
    const short* __restrict__ Gfhi, const short* __restrict__ Gflo,
    const float* __restrict__ bias, const float* __restrict__ fcW,
    const float* __restrict__ fcb,
    short* __restrict__ Yhi, short* __restrict__ Ylo,
    float* __restrict__ yws, int last)
{
    // region reuse: stage T1 [6][4096] (24576 sh) -> U [2][3][64][72] (27648 sh)
    __shared__ short lds[27648];
    const int tid = threadIdx.x, lane = tid & 63;
    const int r16 = lane & 15, q = lane >> 4;
    const int w = __builtin_amdgcn_readfirstlane(tid >> 6);
    const int m = blockIdx.x, b = blockIdx.y, br = blockIdx.z;

    // ---- stage T1 slice (3 o x 2 plane x 4096) into LDS, XOR-swizzled ----
    const size_t t1b = (((size_t)br * 24 + b) * 64 + m) * 4096;
#pragma unroll
    for (int it = 0; it < 12; ++it) {
        int flat = it * 2048 + tid * 8;
        int p2 = flat >> 12;            // o*2 + plane
        int li = flat & 4095;           // c*64 + l
        int c = li >> 6, l = li & 63;
        const short* src = ((p2 & 1) ? T1lo : T1hi) + t1b +
                           (size_t)(p2 >> 1) * 2097152 + li;
        int dst = p2 * 4096 + c * 64 + (l ^ ((c & 7) << 3));
        *(short8*)&lds[dst] = *(const short8*)src;
    }
    __syncthreads();

    // ---- phase 1: U = T1 @ W. Wave w owns combos {w*3..w*3+2} (d*4+ht),
    //      all 4 c-tiles. W-frag loads: 36/wave (no cross-wave redundancy).
    f32x4 acc1[3][4];   // [i][ct]
#pragma unroll
    for (int i = 0; i < 3; ++i)
#pragma unroll
        for (int ct = 0; ct < 4; ++ct)
#pragma unroll
            for (int r = 0; r < 4; ++r) acc1[i][ct][r] = 0.f;

#pragma unroll
    for (int kk = 0; kk < 6; ++kk) {
        const int o = kk >> 1;
        short8 Wh[3], Wl[3];
#pragma unroll
        for (int i = 0; i < 3; ++i) {
            const int combo = w * 3 + i;          // d*4 + ht
            const int d = combo >> 2, ht = combo & 3;
            const int widx = ((((br * 3 + d) * 4 + ht) * 6 + kk) << 9) + lane * 8;
            Wh[i] = *(const short8*)(Wfhi + widx);
            Wl[i] = *(const short8*)(Wflo + widx);
        }
        short8 Ah[4], Al[4];
#pragma unroll
        for (int ct = 0; ct < 4; ++ct) {
            const int c = ct * 16 + r16;
            const int lbase = ((kk & 1) * 32 + q * 8) ^ ((r16 & 7) << 3);
            Ah[ct] = *(const short8*)&lds[(o * 2 + 0) * 4096 + c * 64 + lbase];
            Al[ct] = *(const short8*)&lds[(o * 2 + 1) * 4096 + c * 64 + lbase];
        }
#pragma unroll
        for (int i = 0; i < 3; ++i)
#pragma unroll
            for (int ct = 0; ct < 4; ++ct) {
                acc1[i][ct] = __builtin_amdgcn_mfma_f32_16x16x32_bf16(
                    Ah[ct], Wh[i], acc1[i][ct], 0, 0, 0);
                acc1[i][ct] = __builtin_amdgcn_mfma_f32_16x16x32_bf16(
                    Ah[ct], Wl[i], acc1[i][ct], 0, 0, 0);
                acc1[i][ct] = __builtin_amdgcn_mfma_f32_16x16x32_bf16(
                    Al[ct], Wh[i], acc1[i][ct], 0, 0, 0);
            }
    }
    __syncthreads();   // T1-LDS reads done; region becomes U

    short* u0 = lds;
    short* u1 = lds + 13824;   // 3*64*72
#pragma unroll
    for (int i = 0; i < 3; ++i) {
        const int combo = w * 3 + i;
        const int d = combo >> 2, ht = combo & 3;
        const int h = ht * 16 + r16;
#pragma unroll
        for (int ct = 0; ct < 4; ++ct)
#pragma unroll
            for (int r = 0; r < 4; ++r) {
                float f = acc1[i][ct][r];
                int c = ct * 16 + q * 4 + r;
                int ui = (d * 64 + h) * 72 + c;
                u0[ui] = bf16_hi_trunc(f);
                u1[ui] = bf16_rne(f - trunc_bf16_f32(f));
            }
    }
    __syncthreads();

    // ---- phase 2: out = G^T @ U + bias (wave w owns e-tile w)
    f32x4 acc2[4];
#pragma unroll
    for (int ht = 0; ht < 4; ++ht) {
        float bb = bias[br * 64 + ht * 16 + r16];
#pragma unroll
        for (int r = 0; r < 4; ++r) acc2[ht][r] = bb;
    }
#pragma unroll
    for (int kk = 0; kk < 6; ++kk) {
        const int gi = (((br * 4 + w) * 6 + kk) << 9) + lane * 8;
        short8 A2h = *(const short8*)(Gfhi + gi);
        short8 A2l = *(const short8*)(Gflo + gi);
        const int d = kk >> 1, cb = (kk & 1) * 32 + q * 8;
#pragma unroll
        for (int ht = 0; ht < 4; ++ht) {
            const int bi = (d * 64 + ht * 16 + r16) * 72 + cb;
            short8 B2h = *(const short8*)(u0 + bi);
            short8 B2l = *(const short8*)(u1 + bi);
            acc2[ht] = __builtin_amdgcn_mfma_f32_16x16x32_bf16(
                A2h, B2h, acc2[ht], 0, 0, 0);
            acc2[ht] = __builtin_amdgcn_mfma_f32_16x16x32_bf16(
                A2h, B2l, acc2[ht], 0, 0, 0);
            acc2[ht] = __builtin_amdgcn_mfma_f32_16x16x32_bf16(
                A2l, B2h, acc2[ht], 0, 0, 0);
        }
    }

    if (!last) {
        __syncthreads();
        float* ldsO = (float*)lds;   // 16 KB
#pragma unroll
        for (int ht = 0; ht < 4; ++ht)
#pragma unroll
            for (int r = 0; r < 4; ++r)
                ldsO[(w * 16 + q * 4 + r) * 64 + ht * 16 + r16] = acc2[ht][r];
        __syncthreads();
        const size_t yb = ((size_t)(br * 8 + b) * 64 + m) * 4096;
        const int i0 = tid * 16;
#pragma unroll
        for (int half = 0; half < 2; ++half) {
            short8 h8, l8;
#pragma unroll
            for (int ii = 0; ii < 8; ++ii) {
                float f = ldsO[i0 + half * 8 + ii];
                h8[ii] = bf16_hi_trunc(f);
                l8[ii] = bf16_rne(f - trunc_bf16_f32(f));
            }
            *(short8*)(Yhi + yb + i0 + half * 8) = h8;
            *(short8*)(Ylo + yb + i0 + half * 8) = l8;
        }
    } else {
        float p[4];
#pragma unroll
        for (int r = 0; r < 4; ++r) {
            p[r] = 0.f;
#pragma unroll
            for (int ht = 0; ht < 4; ++ht)
                p[r] += acc2[ht][r] * fcW[br * 64 + ht * 16 + r16];
        }
#pragma unroll
        for (int off = 1; off < 16; off <<= 1)
#pragma unroll
            for (int r = 0; r < 4; ++r) p[r] += __shfl_xor(p[r], off);
        if (r16 == 0) {
            float fb = fcb[br];
#pragma unroll
            for (int r = 0; r < 4; ++r) {
                int e = w * 16 + q * 4 + r;
                yws[(size_t)br * 32768 + (size_t)b * 4096 + m * 64 + e] =
                    fmaxf(p[r] + fb, 0.f);
            }
        }
    }
}

__global__ __launch_bounds__(256) void k_mean(
    const float* __restrict__ yws, float* __restrict__ out)
{
    int idx = blockIdx.x * 256 + threadIdx.x;
    out[idx] = 0.5f * (yws[idx] + yws[32768 + idx]);
}

extern "C" void kernel_launch(void* const* d_in, const int* in_sizes, int n_in,
                              void* d_out, int out_size, void* d_ws, size_t ws_size,
                              hipStream_t stream)
{
    const float* x   = (const float*)d_in[0];
    const float* G   = (const float*)d_in[1];
    const float* wih = (const float*)d_in[2];
    const float* whh = (const float*)d_in[3];
    const float* bih = (const float*)d_in[4];
    const float* bhh = (const float*)d_in[5];
    const float* W0  = (const float*)d_in[6];
    const float* b0  = (const float*)d_in[7];
    const float* W1  = (const float*)d_in[8];
    const float* b1  = (const float*)d_in[9];
    const float* fcW = (const float*)d_in[10];
    const float* fcb = (const float*)d_in[11];
    float* out = (float*)d_out;

    // ws layout (shorts unless noted). Total ~68.2 MB.
    short* Xhi   = (short*)d_ws;            // 4,194,304
    short* Xlo   = Xhi + 4194304;
    short* T1hi  = Xlo + 4194304;           // 12,582,912
    short* T1lo  = T1hi + 12582912;
    float* yws   = (float*)(T1lo + 12582912);  // 65,536 f32
    short* Wfhi  = (short*)(yws + 65536);   // 147,456
    short* Wflo  = Wfhi + 147456;
    short* Gfhi  = Wflo + 147456;           // 24,576
    short* Gflo  = Gfhi + 24576;
    short* Whfhi = Gflo + 24576;            // 32,768
    short* Whflo = Whfhi + 32768;
    short* Y1hi  = Xhi;                     // reuse (X dead after layer-1 k_t1)
    short* Y1lo  = Xlo;

    k_prep<<<800, 256, 0, stream>>>(G, W0, W1, whh,
                                    Wfhi, Wflo, Gfhi, Gflo, Whfhi, Whflo);
    k_lstm<<<dim3(2048, 2), 256, 0, stream>>>(x, Whfhi, Whflo, wih, bih, bhh,
                                              Xhi, Xlo);

    // layer 1
    k_t1<<<dim3(16, 24, 2), 256, 0, stream>>>(Xhi, Xlo, G, T1hi, T1lo);
    k_t2fc<<<dim3(64, 8, 2), 256, 0, stream>>>(T1hi, T1lo, Wfhi, Wflo,
                                               Gfhi, Gflo, b0, fcW, fcb,
                                               Y1hi, Y1lo, yws, 0);
    // layer 2
    k_t1<<<dim3(16, 24, 2), 256, 0, stream>>>(Y1hi, Y1lo, G, T1hi, T1lo);
    k_t2fc<<<dim3(64, 8, 2), 256, 0, stream>>>(T1hi, T1lo,
                                               Wfhi + 73728, Wflo + 73728,
                                               Gfhi, Gflo, b1, fcW, fcb,
                                               (short*)nullptr, (short*)nullptr,
                                               yws, 1);
    k_mean<<<128, 256, 0, stream>>>(yws, out);
}

// Round 8
// 278.666 us; speedup vs baseline: 1.4585x; 1.0930x over previous
//
#include <hip/hip_runtime.h>
#include <hip/hip_bf16.h>

// M=2 branches, K=3 diffusion, N=64, I=1, H=64, B=8, T=12

typedef __attribute__((ext_vector_type(8))) short short8;   // 8 bf16 (4 VGPRs)
typedef __attribute__((ext_vector_type(4))) float f32x4;    // 4 fp32

__device__ __forceinline__ short bf16_hi_trunc(float f) {
    union { float f; unsigned u; } v; v.f = f;
    return (short)(v.u >> 16);
}
__device__ __forceinline__ float trunc_bf16_f32(float f) {
    union { float f; unsigned u; } v; v.f = f;
    v.u &= 0xFFFF0000u;
    return v.f;
}
__device__ __forceinline__ short bf16_rne(float f) {
    union { float f; unsigned u; } v; v.f = f;
    unsigned r = ((v.u >> 16) & 1u) + 0x7FFFu;
    return (short)((v.u + r) >> 16);
}
__device__ __forceinline__ float from_bf16(unsigned short s) {
    union { unsigned u; float f; } v; v.u = ((unsigned)s) << 16;
    return v.f;
}
__device__ __forceinline__ float sigmoidf_(float x) {
    float e = __builtin_amdgcn_exp2f(x * -1.442695041f);
    return __builtin_amdgcn_rcpf(1.f + e);
}
__device__ __forceinline__ float tanhf_(float x) {
    float e2 = __builtin_amdgcn_exp2f(x * 2.885390082f);
    return fmaf(-2.f, __builtin_amdgcn_rcpf(e2 + 1.f), 1.f);
}

// ---------------- prep: pack W, G^T, Whh into MFMA fragment order ----------
// Wf [layer][br][d][ht][kk][lane][8] : 147456/plane
// Gf [br][et][kk][lane][8]           : 24576/plane
// Whf[br][kt][gg][w][lane][8]        : 32768/plane  (B[k][gate] of WhhT)
__global__ __launch_bounds__(256) void k_prep(
    const float* __restrict__ G, const float* __restrict__ W0,
    const float* __restrict__ W1, const float* __restrict__ whh,
    short* __restrict__ Wfhi, short* __restrict__ Wflo,
    short* __restrict__ Gfhi, short* __restrict__ Gflo,
    short* __restrict__ Whfhi, short* __restrict__ Whflo)
{
    int idx = blockIdx.x * 256 + threadIdx.x;
    float v; short *dh, *dl; int didx;
    if (idx < 147456) {
        int j = idx & 7, lane = (idx >> 3) & 63, kk = (idx >> 9) % 6;
        int t2 = idx / 3072;
        int ht = t2 & 3; t2 >>= 2;
        int d = t2 % 3; t2 /= 3;
        int br = t2 & 1, layer = t2 >> 1;
        int k = kk * 32 + ((lane >> 4) << 3) + j;
        int o = k >> 6, l = k & 63, h = ht * 16 + (lane & 15);
        const float* Wp = layer ? W1 : W0;
        v = Wp[((size_t)br * 576 + (o * 3 + d) * 64 + l) * 64 + h];
        dh = Wfhi; dl = Wflo; didx = idx;
    } else if (idx < 172032) {
        int i2 = idx - 147456;
        int j = i2 & 7, lane = (i2 >> 3) & 63, kk = (i2 >> 9) % 6;
        int t2 = i2 / 3072;
        int et = t2 & 3, br = t2 >> 2;
        int k = kk * 32 + ((lane >> 4) << 3) + j;
        int d = k >> 6, c = k & 63, e = et * 16 + (lane & 15);
        v = G[(((size_t)br * 3 + d) * 64 + c) * 64 + e];
        dh = Gfhi; dl = Gflo; didx = i2;
    } else {
        int i3 = idx - 172032;
        int j = i3 & 7, lane = (i3 >> 3) & 63;
        int w = (i3 >> 9) & 3, gg = (i3 >> 11) & 3;
        int kt = (i3 >> 13) & 1, br = (i3 >> 14) & 1;
        int gate = gg * 64 + w * 16 + (lane & 15);
        int k = kt * 32 + ((lane >> 4) << 3) + j;
        v = whh[((size_t)br * 256 + gate) * 64 + k];
        dh = Whfhi; dl = Whflo; didx = i3;
    }
    dh[didx] = bf16_hi_trunc(v);
    dl[didx] = bf16_rne(v - trunc_bf16_f32(v));
}

// ---------------- LSTM v4.1: 16 seqs/block, 4 waves, register weights ------
// Block = (br, b, o, dg). Wave w owns gate cols {gg*64 + w*16 .. +15}.
// B-frags register-resident (64 VGPR); launch_bounds(256,3) -> 170-reg
// budget so the full ~118-reg live set fits WITHOUT scratch spills
// (round-7 (256,4) capped at 128 total incl. AGPR -> 50 MB spill traffic).
__global__ __launch_bounds__(256, 3) void k_lstm(
    const float* __restrict__ x, const short* __restrict__ Whfhi,
    const short* __restrict__ Whflo, const float* __restrict__ wih,
    const float* __restrict__ bih, const float* __restrict__ bhh,
    short* __restrict__ Xhi, short* __restrict__ Xlo)
{
    __shared__ short hbuf[2][2][16][64];   // [dbuf][plane][seq][hid^swz] 8 KB
    const int tid = threadIdx.x;
    const int lane = tid & 63;
    const int w = __builtin_amdgcn_readfirstlane(tid >> 6);   // gate slice 0..3
    const int q = lane >> 4, r16 = lane & 15;
    const int br = blockIdx.y;
    const int bx = blockIdx.x;
    const int dg = bx & 3, o = (bx >> 2) & 63, b = bx >> 8;

    // weight-stationary B fragments (hi/lo), statically indexed -> registers
    short8 Bh[2][4], Bl[2][4];
    {
        const short* wbh = Whfhi + (size_t)br * 16384;
        const short* wbl = Whflo + (size_t)br * 16384;
#pragma unroll
        for (int kt = 0; kt < 2; ++kt)
#pragma unroll
            for (int gg = 0; gg < 4; ++gg) {
                const int bidx = (((kt * 4 + gg) * 4 + w) * 64 + lane) * 8;
                Bh[kt][gg] = *(const short8*)(wbh + bidx);
                Bl[kt][gg] = *(const short8*)(wbl + bidx);
            }
    }

    float wihv[4], biasv[4];
#pragma unroll
    for (int gg = 0; gg < 4; ++gg) {
        const int gate = gg * 64 + w * 16 + r16;
        wihv[gg] = wih[br * 256 + gate];
        biasv[gg] = bih[br * 256 + gate] + bhh[br * 256 + gate];
    }

    float cst[4] = {0.f, 0.f, 0.f, 0.f};
    const float* xb = x + (size_t)b * 12 * 4096 + o * 64 + dg * 16;
    const size_t hob = ((size_t)(br * 8 + b) * 64 + o) * 4096 + dg * 1024;
    const int hid = w * 16 + r16;

    for (int t = 0; t < 12; ++t) {
        f32x4 acc[4];   // [gg]
        float4 xv = *(const float4*)(xb + (size_t)t * 4096 + q * 4);
        float xm[4] = {xv.x, xv.y, xv.z, xv.w};
#pragma unroll
        for (int r = 0; r < 4; ++r)
#pragma unroll
            for (int gg = 0; gg < 4; ++gg)
                acc[gg][r] = fmaf(xm[r], wihv[gg], biasv[gg]);

        if (t > 0) {
            const short* hb0 = &hbuf[t & 1][0][0][0];
#pragma unroll
            for (int kt = 0; kt < 2; ++kt) {
                const int col = (kt * 32 + q * 8) ^ ((r16 & 7) << 3);
                short8 Ah = *(const short8*)&hb0[r16 * 64 + col];
                short8 Al = *(const short8*)&hb0[1024 + r16 * 64 + col];
#pragma unroll
                for (int gg = 0; gg < 4; ++gg) {
                    acc[gg] = __builtin_amdgcn_mfma_f32_16x16x32_bf16(
                        Ah, Bh[kt][gg], acc[gg], 0, 0, 0);
                    acc[gg] = __builtin_amdgcn_mfma_f32_16x16x32_bf16(
                        Ah, Bl[kt][gg], acc[gg], 0, 0, 0);
                    acc[gg] = __builtin_amdgcn_mfma_f32_16x16x32_bf16(
                        Al, Bh[kt][gg], acc[gg], 0, 0, 0);
                }
            }
        }
        // activations (torch gate order i,f,g,o); lane owns seq=q*4+r, hid
        float hv_[4];
#pragma unroll
        for (int r = 0; r < 4; ++r) {
            float ig = sigmoidf_(acc[0][r]);
            float fg = sigmoidf_(acc[1][r]);
            float gt = tanhf_(acc[2][r]);
            float og = sigmoidf_(acc[3][r]);
            float c = fmaf(fg, cst[r], ig * gt);
            cst[r] = c;
            hv_[r] = og * tanhf_(c);
        }
        if (t == 11) {
#pragma unroll
            for (int r = 0; r < 4; ++r) {
                int seq = q * 4 + r;
                float hv = hv_[r];
                Xhi[hob + seq * 64 + hid] = bf16_hi_trunc(hv);
                Xlo[hob + seq * 64 + hid] = bf16_rne(hv - trunc_bf16_f32(hv));
            }
        } else {
            short* hw0 = &hbuf[(t + 1) & 1][0][0][0];
#pragma unroll
            for (int r = 0; r < 4; ++r) {
                int seq = q * 4 + r;
                int col = hid ^ ((seq & 7) << 3);
                float hv = hv_[r];
                hw0[seq * 64 + col] = bf16_hi_trunc(hv);
                hw0[1024 + seq * 64 + col] = bf16_rne(hv - trunc_bf16_f32(hv));
            }
            __syncthreads();   // single barrier per step (dbuf)
        }
    }
}

// ---------------- T1 (VALU fp32, hi/lo bf16 I/O) ---------------------------
// T1[br][o][b][m][cl] = sum_n G[br][o][n][m] * X[br][b][n][cl]
__global__ __launch_bounds__(256) void k_t1(
    const short* __restrict__ Xhi, const short* __restrict__ Xlo,
    const float* __restrict__ G,
    short* __restrict__ T1hi, short* __restrict__ T1lo)
{
    const int br = blockIdx.z;
    const int o = blockIdx.y >> 3, b = blockIdx.y & 7;
    const int cl = blockIdx.x * 256 + threadIdx.x;
    const unsigned short* xh = (const unsigned short*)Xhi;
    const unsigned short* xl = (const unsigned short*)Xlo;
    const size_t xb = ((size_t)(br * 8 + b) * 64) * 4096 + cl;
    const float* gp = G + ((size_t)(br * 3 + o) * 64) * 64;
    float acc[64];
#pragma unroll
    for (int mm = 0; mm < 64; ++mm) acc[mm] = 0.f;
#pragma unroll 4
    for (int n = 0; n < 64; ++n) {
        float xv = from_bf16(xh[xb + (size_t)n * 4096]) +
                   from_bf16(xl[xb + (size_t)n * 4096]);
        const float* gr = gp + n * 64;
#pragma unroll
        for (int mm = 0; mm < 64; ++mm) acc[mm] = fmaf(xv, gr[mm], acc[mm]);
    }
    const size_t tb = (((size_t)(br * 3 + o) * 8 + b) * 64) * 4096 + cl;
#pragma unroll
    for (int mm = 0; mm < 64; ++mm) {
        float f = acc[mm];
        T1hi[tb + (size_t)mm * 4096] = bf16_hi_trunc(f);
        T1lo[tb + (size_t)mm * 4096] = bf16_rne(f - trunc_bf16_f32(f));
    }
}

// ---------------- T2 + FC (MFMA), LDS-staged T1, wave-split W --------------
// Per (br,b,m): U[d][c][h] = sum_{o,l} T1[o][c][l] W[(o,d)l][h]   (phase 1)
//              out[e][h]  = bias[h] + sum_{d,c} G[d][c][e] U[d][c][h] (ph 2)
__global__ __launch_bounds__(256) void k_t2fc(
    const short* __restrict__ T1hi, const short* __restrict__ T1lo,
    const short* __restrict__ Wfhi, const short* __restrict__ Wflo,
    const short* __restrict__ Gfhi, const short* __restrict__ Gflo,
    const float* __restrict__ bias, const float* __restrict__ fcW,
    const float* __restrict__ fcb,
    short* __restrict__ Yhi, short* __restrict__ Ylo,
    float* __restrict__ yws, int last)
{
    // region reuse: stage T1 [6][4096] (24576 sh) -> U [2][3][64][72] (27648 sh)
    __shared__ short lds[27648];
    const int tid = threadIdx.x, lane = tid & 63;
    const int r16 = lane & 15, q = lane >> 4;
    const int w = __builtin_amdgcn_readfirstlane(tid >> 6);
    const int m = blockIdx.x, b = blockIdx.y, br = blockIdx.z;

    // ---- stage T1 slice (3 o x 2 plane x 4096) into LDS, XOR-swizzled ----
    const size_t t1b = (((size_t)br * 24 + b) * 64 + m) * 4096;
#pragma unroll
    for (int it = 0; it < 12; ++it) {
        int flat = it * 2048 + tid * 8;
        int p2 = flat >> 12;            // o*2 + plane
        int li = flat & 4095;           // c*64 + l
        int c = li >> 6, l = li & 63;
        const short* src = ((p2 & 1) ? T1lo : T1hi) + t1b +
                           (size_t)(p2 >> 1) * 2097152 + li;
        int dst = p2 * 4096 + c * 64 + (l ^ ((c & 7) << 3));
        *(short8*)&lds[dst] = *(const short8*)src;
    }
    __syncthreads();

    // ---- phase 1: U = T1 @ W. Wave w owns combos {w*3..w*3+2} (d*4+ht),
    //      all 4 c-tiles. W-frag loads: 36/wave (no cross-wave redundancy).
    f32x4 acc1[3][4];   // [i][ct]
#pragma unroll
    for (int i = 0; i < 3; ++i)
#pragma unroll
        for (int ct = 0; ct < 4; ++ct)
#pragma unroll
            for (int r = 0; r < 4; ++r) acc1[i][ct][r] = 0.f;

#pragma unroll
    for (int kk = 0; kk < 6; ++kk) {
        const int o = kk >> 1;
        short8 Wh[3], Wl[3];
#pragma unroll
        for (int i = 0; i < 3; ++i) {
            const int combo = w * 3 + i;          // d*4 + ht
            const int d = combo >> 2, ht = combo & 3;
            const int widx = ((((br * 3 + d) * 4 + ht) * 6 + kk) << 9) + lane * 8;
            Wh[i] = *(const short8*)(Wfhi + widx);
            Wl[i] = *(const short8*)(Wflo + widx);
        }
        short8 Ah[4], Al[4];
#pragma unroll
        for (int ct = 0; ct < 4; ++ct) {
            const int c = ct * 16 + r16;
            const int lbase = ((kk & 1) * 32 + q * 8) ^ ((r16 & 7) << 3);
            Ah[ct] = *(const short8*)&lds[(o * 2 + 0) * 4096 + c * 64 + lbase];
            Al[ct] = *(const short8*)&lds[(o * 2 + 1) * 4096 + c * 64 + lbase];
        }
#pragma unroll
        for (int i = 0; i < 3; ++i)
#pragma unroll
            for (int ct = 0; ct < 4; ++ct) {
                acc1[i][ct] = __builtin_amdgcn_mfma_f32_16x16x32_bf16(
                    Ah[ct], Wh[i], acc1[i][ct], 0, 0, 0);
                acc1[i][ct] = __builtin_amdgcn_mfma_f32_16x16x32_bf16(
                    Ah[ct], Wl[i], acc1[i][ct], 0, 0, 0);
                acc1[i][ct] = __builtin_amdgcn_mfma_f32_16x16x32_bf16(
                    Al[ct], Wh[i], acc1[i][ct], 0, 0, 0);
            }
    }
    __syncthreads();   // T1-LDS reads done; region becomes U

    short* u0 = lds;
    short* u1 = lds + 13824;   // 3*64*72
#pragma unroll
    for (int i = 0; i < 3; ++i) {
        const int combo = w * 3 + i;
        const int d = combo >> 2, ht = combo & 3;
        const int h = ht * 16 + r16;
#pragma unroll
        for (int ct = 0; ct < 4; ++ct)
#pragma unroll
            for (int r = 0; r < 4; ++r) {
                float f = acc1[i][ct][r];
                int c = ct * 16 + q * 4 + r;
                int ui = (d * 64 + h) * 72 + c;
                u0[ui] = bf16_hi_trunc(f);
                u1[ui] = bf16_rne(f - trunc_bf16_f32(f));
            }
    }
    __syncthreads();

    // ---- phase 2: out = G^T @ U + bias (wave w owns e-tile w)
    f32x4 acc2[4];
#pragma unroll
    for (int ht = 0; ht < 4; ++ht) {
        float bb = bias[br * 64 + ht * 16 + r16];
#pragma unroll
        for (int r = 0; r < 4; ++r) acc2[ht][r] = bb;
    }
#pragma unroll
    for (int kk = 0; kk < 6; ++kk) {
        const int gi = (((br * 4 + w) * 6 + kk) << 9) + lane * 8;
        short8 A2h = *(const short8*)(Gfhi + gi);
        short8 A2l = *(const short8*)(Gflo + gi);
        const int d = kk >> 1, cb = (kk & 1) * 32 + q * 8;
#pragma unroll
        for (int ht = 0; ht < 4; ++ht) {
            const int bi = (d * 64 + ht * 16 + r16) * 72 + cb;
            short8 B2h = *(const short8*)(u0 + bi);
            short8 B2l = *(const short8*)(u1 + bi);
            acc2[ht] = __builtin_amdgcn_mfma_f32_16x16x32_bf16(
                A2h, B2h, acc2[ht], 0, 0, 0);
            acc2[ht] = __builtin_amdgcn_mfma_f32_16x16x32_bf16(
                A2h, B2l, acc2[ht], 0, 0, 0);
            acc2[ht] = __builtin_amdgcn_mfma_f32_16x16x32_bf16(
                A2l, B2h, acc2[ht], 0, 0, 0);
        }
    }

    if (!last) {
        __syncthreads();
        float* ldsO = (float*)lds;   // 16 KB
#pragma unroll
        for (int ht = 0; ht < 4; ++ht)
#pragma unroll
            for (int r = 0; r < 4; ++r)
                ldsO[(w * 16 + q * 4 + r) * 64 + ht * 16 + r16] = acc2[ht][r];
        __syncthreads();
        const size_t yb = ((size_t)(br * 8 + b) * 64 + m) * 4096;
        const int i0 = tid * 16;
#pragma unroll
        for (int half = 0; half < 2; ++half) {
            short8 h8, l8;
#pragma unroll
            for (int ii = 0; ii < 8; ++ii) {
                float f = ldsO[i0 + half * 8 + ii];
                h8[ii] = bf16_hi_trunc(f);
                l8[ii] = bf16_rne(f - trunc_bf16_f32(f));
            }
            *(short8*)(Yhi + yb + i0 + half * 8) = h8;
            *(short8*)(Ylo + yb + i0 + half * 8) = l8;
        }
    } else {
        float p[4];
#pragma unroll
        for (int r = 0; r < 4; ++r) {
            p[r] = 0.f;
#pragma unroll
            for (int ht = 0; ht < 4; ++ht)
                p[r] += acc2[ht][r] * fcW[br * 64 + ht * 16 + r16];
        }
#pragma unroll
        for (int off = 1; off < 16; off <<= 1)
#pragma unroll
            for (int r = 0; r < 4; ++r) p[r] += __shfl_xor(p[r], off);
        if (r16 == 0) {
            float fb = fcb[br];
#pragma unroll
            for (int r = 0; r < 4; ++r) {
                int e = w * 16 + q * 4 + r;
                yws[(size_t)br * 32768 + (size_t)b * 4096 + m * 64 + e] =
                    fmaxf(p[r] + fb, 0.f);
            }
        }
    }
}

__global__ __launch_bounds__(256) void k_mean(
    const float* __restrict__ yws, float* __restrict__ out)
{
    int idx = blockIdx.x * 256 + threadIdx.x;
    out[idx] = 0.5f * (yws[idx] + yws[32768 + idx]);
}

extern "C" void kernel_launch(void* const* d_in, const int* in_sizes, int n_in,
                              void* d_out, int out_size, void* d_ws, size_t ws_size,
                              hipStream_t stream)
{
    const float* x   = (const float*)d_in[0];
    const float* G   = (const float*)d_in[1];
    const float* wih = (const float*)d_in[2];
    const float* whh = (const float*)d_in[3];
    const float* bih = (const float*)d_in[4];
    const float* bhh = (const float*)d_in[5];
    const float* W0  = (const float*)d_in[6];
    const float* b0  = (const float*)d_in[7];
    const float* W1  = (const float*)d_in[8];
    const float* b1  = (const float*)d_in[9];
    const float* fcW = (const float*)d_in[10];
    const float* fcb = (const float*)d_in[11];
    float* out = (float*)d_out;

    // ws layout (shorts unless noted). Total ~68.2 MB.
    short* Xhi   = (short*)d_ws;            // 4,194,304
    short* Xlo   = Xhi + 4194304;
    short* T1hi  = Xlo + 4194304;           // 12,582,912
    short* T1lo  = T1hi + 12582912;
    float* yws   = (float*)(T1lo + 12582912);  // 65,536 f32
    short* Wfhi  = (short*)(yws + 65536);   // 147,456
    short* Wflo  = Wfhi + 147456;
    short* Gfhi  = Wflo + 147456;           // 24,576
    short* Gflo  = Gfhi + 24576;
    short* Whfhi = Gflo + 24576;            // 32,768
    short* Whflo = Whfhi + 32768;
    short* Y1hi  = Xhi;                     // reuse (X dead after layer-1 k_t1)
    short* Y1lo  = Xlo;

    k_prep<<<800, 256, 0, stream>>>(G, W0, W1, whh,
                                    Wfhi, Wflo, Gfhi, Gflo, Whfhi, Whflo);
    k_lstm<<<dim3(2048, 2), 256, 0, stream>>>(x, Whfhi, Whflo, wih, bih, bhh,
                                              Xhi, Xlo);

    // layer 1
    k_t1<<<dim3(16, 24, 2), 256, 0, stream>>>(Xhi, Xlo, G, T1hi, T1lo);
    k_t2fc<<<dim3(64, 8, 2), 256, 0, stream>>>(T1hi, T1lo, Wfhi, Wflo,
                                               Gfhi, Gflo, b0, fcW, fcb,
                                               Y1hi, Y1lo, yws, 0);
    // layer 2
    k_t1<<<dim3(16, 24, 2), 256, 0, stream>>>(Y1hi, Y1lo, G, T1hi, T1lo);
    k_t2fc<<<dim3(64, 8, 2), 256, 0, stream>>>(T1hi, T1lo,
                                               Wfhi + 73728, Wflo + 73728,
                                               Gfhi, Gflo, b1, fcW, fcb,
                                               (short*)nullptr, (short*)nullptr,
                                               yws, 1);
    k_mean<<<128, 256, 0, stream>>>(yws, out);
}